// Round 1
// baseline (802.080 us; speedup 1.0000x reference)
//
#include <hip/hip_runtime.h>

#define NN 4096
#define HEADS 4
#define H1PER 30
#define H1DIM 120
#define H2DIM 50

__device__ __forceinline__ float lrelu(float x) { return x > 0.f ? x : 0.1f * x; }

// ---------------- bitmask: adj(int32) -> 1 bit ----------------
__global__ __launch_bounds__(256) void k_bits(const int* __restrict__ adj,
                                              unsigned long long* __restrict__ bits) {
  int e = blockIdx.x * 256 + threadIdx.x;
  unsigned long long m = __ballot(adj[e] > 0);
  if ((threadIdx.x & 63) == 0) bits[e >> 6] = m;
}

// ---------------- GEMM1: partial wh1 = x @ W1 (K-split 2) ----------------
// grid (64 rowblocks, 4 heads, 2 ksplit), block 256
__global__ __launch_bounds__(256) void k_gemm1(const float* __restrict__ x,
                                               const float* __restrict__ W1,
                                               float* __restrict__ part) {
  const int h = blockIdx.y, z = blockIdx.z;
  const int i0 = blockIdx.x * 64;
  const int t = threadIdx.x;
  const int o = t & 31, rg = t >> 5;  // 8 row-groups x 8 rows
  __shared__ float xs[64][68];        // transposed x tile [kk][r]
  __shared__ float wt[64][32];
  float acc[8];
#pragma unroll
  for (int q = 0; q < 8; ++q) acc[q] = 0.f;
  const int r_ld = t >> 2;
  const int kb_ld = (t & 3) * 16;
  float* pz = part + (size_t)z * (HEADS * NN * H1PER);
  for (int kc = z * 2048; kc < z * 2048 + 2048; kc += 64) {
    const float* xp = x + (size_t)(i0 + r_ld) * 4096 + kc + kb_ld;
#pragma unroll
    for (int v = 0; v < 4; ++v) {
      float4 xv = *(const float4*)(xp + v * 4);
      xs[kb_ld + v * 4 + 0][r_ld] = xv.x;
      xs[kb_ld + v * 4 + 1][r_ld] = xv.y;
      xs[kb_ld + v * 4 + 2][r_ld] = xv.z;
      xs[kb_ld + v * 4 + 3][r_ld] = xv.w;
    }
    const float* wp = W1 + (size_t)(h * 4096 + kc) * H1PER;
    for (int e = t; e < 64 * H1PER; e += 256) wt[e / H1PER][e % H1PER] = wp[e];
    __syncthreads();
#pragma unroll 4
    for (int kk = 0; kk < 64; ++kk) {
      float wv = wt[kk][o];
      const float4 xa = *(const float4*)&xs[kk][rg * 8];
      const float4 xb = *(const float4*)&xs[kk][rg * 8 + 4];
      acc[0] += xa.x * wv; acc[1] += xa.y * wv; acc[2] += xa.z * wv; acc[3] += xa.w * wv;
      acc[4] += xb.x * wv; acc[5] += xb.y * wv; acc[6] += xb.z * wv; acc[7] += xb.w * wv;
    }
    __syncthreads();
  }
  if (o < H1PER) {
    float* pp = pz + ((size_t)h * NN + i0) * H1PER;
#pragma unroll
    for (int q = 0; q < 8; ++q) pp[(rg * 8 + q) * H1PER + o] = acc[q];
  }
}

// ---------------- combine partials + f1/f2 ----------------
__global__ __launch_bounds__(256) void k_f1(const float* __restrict__ p0, const float* __restrict__ p1,
                                            const float* __restrict__ a1s, const float* __restrict__ a1d,
                                            float* __restrict__ wh1, float* __restrict__ f1,
                                            float* __restrict__ f2) {
  int id = blockIdx.x * 256 + threadIdx.x;  // h*4096+n
  if (id >= HEADS * NN) return;
  int h = id >> 12;
  const float* s = a1s + h * H1PER;
  const float* dv = a1d + h * H1PER;
  const float* q0 = p0 + (size_t)id * H1PER;
  const float* q1 = p1 + (size_t)id * H1PER;
  float* o = wh1 + (size_t)id * H1PER;
  float accs = 0.f, accd = 0.f;
#pragma unroll
  for (int j = 0; j < H1PER; ++j) {
    float v = q0[j] + q1[j];
    o[j] = v;
    accs += v * s[j];
    accd += v * dv[j];
  }
  f1[id] = accs;
  f2[id] = accd;
}

// ---------------- per-row max over 4096 values ----------------
__global__ __launch_bounds__(256) void k_max(const float* __restrict__ v, float* __restrict__ mx) {
  int t = threadIdx.x;
  const float* row = v + (size_t)blockIdx.x * NN;
  float m = -3.0e38f;
  for (int n = t; n < NN; n += 256) m = fmaxf(m, row[n]);
  for (int off = 32; off > 0; off >>= 1) m = fmaxf(m, __shfl_down(m, off));
  __shared__ float ms[4];
  if ((t & 63) == 0) ms[t >> 6] = m;
  __syncthreads();
  if (t == 0) mx[blockIdx.x] = fmaxf(fmaxf(ms[0], ms[1]), fmaxf(ms[2], ms[3]));
}

// ---------------- fused GAT layer 1 attention ----------------
// grid (128 rowblocks(32 rows), 4 heads), block 256
__global__ __launch_bounds__(256) void k_att1(const float* __restrict__ wh1, const float* __restrict__ f1,
                                              const float* __restrict__ f2, const float* __restrict__ mx,
                                              const unsigned long long* __restrict__ bits,
                                              const float* __restrict__ b1, float* __restrict__ h1) {
  const int h = blockIdx.y;
  const int i0 = blockIdx.x * 32;
  const int t = threadIdx.x;
  __shared__ float whs[128][32];
  __shared__ float wls[32][132];
  __shared__ float f2s[128];
  __shared__ float f1s[32], ms_[32], lsum[32];
  __shared__ float lred[32][8];
  if (t < 32) {
    float fv = f1[h * NN + i0 + t];
    f1s[t] = fv;
    ms_[t] = lrelu(fv + mx[h]);
  }
  __syncthreads();
  const int rw = t >> 3, js = t & 7;  // also compute mapping: row rw, o-group js
  const float f1r = f1s[rw], mr = ms_[rw];
  float lpart = 0.f;
  float acc[4] = {0.f, 0.f, 0.f, 0.f};
  const float* whbase = wh1 + (size_t)h * NN * H1PER;
  for (int tile = 0; tile < 32; ++tile) {
    const int j0 = tile * 128;
    const float* wp = whbase + (size_t)j0 * H1PER;
    for (int e = t; e < 128 * H1PER; e += 256) whs[e / H1PER][e % H1PER] = wp[e];
    if (t < 128) {
      whs[t][30] = 0.f;
      whs[t][31] = 0.f;
      f2s[t] = f2[h * NN + j0 + t];
    }
    __syncthreads();
    unsigned long long wb = bits[(size_t)(i0 + rw) * 64 + (j0 >> 6) + (js >> 2)];
    int bitbase = (js & 3) * 16;
#pragma unroll
    for (int q = 0; q < 16; ++q) {
      int jt = js * 16 + q;
      float ev = lrelu(f1r + f2s[jt]) - mr;
      float wv = ((wb >> (bitbase + q)) & 1ULL) ? __expf(ev) : 0.f;
      lpart += wv;
      wls[rw][jt] = wv;
    }
    __syncthreads();
#pragma unroll 2
    for (int jt = 0; jt < 128; jt += 4) {
      float4 wv = *(const float4*)&wls[rw][jt];
      float4 a0 = *(const float4*)&whs[jt + 0][js * 4];
      float4 a1 = *(const float4*)&whs[jt + 1][js * 4];
      float4 a2 = *(const float4*)&whs[jt + 2][js * 4];
      float4 a3 = *(const float4*)&whs[jt + 3][js * 4];
      acc[0] += wv.x * a0.x; acc[1] += wv.x * a0.y; acc[2] += wv.x * a0.z; acc[3] += wv.x * a0.w;
      acc[0] += wv.y * a1.x; acc[1] += wv.y * a1.y; acc[2] += wv.y * a1.z; acc[3] += wv.y * a1.w;
      acc[0] += wv.z * a2.x; acc[1] += wv.z * a2.y; acc[2] += wv.z * a2.z; acc[3] += wv.z * a2.w;
      acc[0] += wv.w * a3.x; acc[1] += wv.w * a3.y; acc[2] += wv.w * a3.z; acc[3] += wv.w * a3.w;
    }
    __syncthreads();
  }
  lred[rw][js] = lpart;
  __syncthreads();
  if (t < 32) {
    float s = 0.f;
#pragma unroll
    for (int q = 0; q < 8; ++q) s += lred[t][q];
    lsum[t] = s;
  }
  __syncthreads();
  const float linv = 1.f / lsum[rw];
#pragma unroll
  for (int oo = 0; oo < 4; ++oo) {
    int o = js * 4 + oo;
    if (o < H1PER)
      h1[(size_t)(i0 + rw) * H1DIM + h * H1PER + o] = lrelu(acc[oo] * linv + b1[h * H1PER + o]);
  }
}

// ---------------- GEMM2: wh2 = h1 @ W2 ----------------
__global__ __launch_bounds__(256) void k_gemm2(const float* __restrict__ h1, const float* __restrict__ W2,
                                               float* __restrict__ wh2) {
  const int n0 = blockIdx.x * 4;
  const int t = threadIdx.x;
  const int o = t & 63, r = t >> 6;
  __shared__ float hs[4][120];
  for (int e = t; e < 4 * H1DIM; e += 256) hs[e / H1DIM][e % H1DIM] = h1[(size_t)n0 * H1DIM + e];
  __syncthreads();
  if (o < H2DIM) {
    float acc = 0.f;
#pragma unroll 4
    for (int k = 0; k < H1DIM; ++k) acc += hs[r][k] * W2[k * H2DIM + o];
    wh2[(size_t)(n0 + r) * H2DIM + o] = acc;
  }
}

__global__ __launch_bounds__(256) void k_f2l2(const float* __restrict__ wh2, const float* __restrict__ a2s,
                                              const float* __restrict__ a2d, float* __restrict__ f1,
                                              float* __restrict__ f2) {
  int n = blockIdx.x * 256 + threadIdx.x;
  if (n >= NN) return;
  const float* r = wh2 + (size_t)n * H2DIM;
  float accs = 0.f, accd = 0.f;
#pragma unroll
  for (int j = 0; j < H2DIM; ++j) {
    float v = r[j];
    accs += v * a2s[j];
    accd += v * a2d[j];
  }
  f1[n] = accs;
  f2[n] = accd;
}

// ---------------- fused GAT layer 2 attention (partials over j-halves) ----------------
// grid (256 rowblocks(16 rows), 2 j-halves), block 256
__global__ __launch_bounds__(256) void k_att2(const float* __restrict__ wh2, const float* __restrict__ f1,
                                              const float* __restrict__ f2, const float* __restrict__ mx,
                                              const unsigned long long* __restrict__ bits,
                                              float* __restrict__ pacc, float* __restrict__ pl) {
  const int jh = blockIdx.y;
  const int i0 = blockIdx.x * 16;
  const int t = threadIdx.x;
  __shared__ float whs[128][64];
  __shared__ float wls[16][132];
  __shared__ float f2s[128];
  __shared__ float f1s[16], ms_[16];
  __shared__ float lred[16][16];
  if (t < 16) {
    float fv = f1[i0 + t];
    f1s[t] = fv;
    ms_[t] = lrelu(fv + mx[0]);
  }
  __syncthreads();
  const int rw = t >> 4, js = t & 15;  // compute mapping: row rw, o-group js (o=js*4..+3)
  const float f1r = f1s[rw], mr = ms_[rw];
  float lpart = 0.f;
  float acc[4] = {0.f, 0.f, 0.f, 0.f};
  for (int tile = 0; tile < 16; ++tile) {
    const int j0 = jh * 2048 + tile * 128;
    const float* wp = wh2 + (size_t)j0 * H2DIM;
    for (int e = t; e < 128 * 64; e += 256) {
      int jt = e >> 6, o = e & 63;
      whs[jt][o] = (o < H2DIM) ? wp[jt * H2DIM + o] : 0.f;
    }
    if (t < 128) f2s[t] = f2[j0 + t];
    __syncthreads();
    unsigned long long wb = bits[(size_t)(i0 + rw) * 64 + (j0 >> 6) + (js >> 3)];
    int bitbase = (js & 7) * 8;
#pragma unroll
    for (int q = 0; q < 8; ++q) {
      int jt = js * 8 + q;
      float ev = lrelu(f1r + f2s[jt]) - mr;
      float wv = ((wb >> (bitbase + q)) & 1ULL) ? __expf(ev) : 0.f;
      lpart += wv;
      wls[rw][jt] = wv;
    }
    __syncthreads();
#pragma unroll 2
    for (int jt = 0; jt < 128; jt += 4) {
      float4 wv = *(const float4*)&wls[rw][jt];
      float4 a0 = *(const float4*)&whs[jt + 0][js * 4];
      float4 a1 = *(const float4*)&whs[jt + 1][js * 4];
      float4 a2 = *(const float4*)&whs[jt + 2][js * 4];
      float4 a3 = *(const float4*)&whs[jt + 3][js * 4];
      acc[0] += wv.x * a0.x; acc[1] += wv.x * a0.y; acc[2] += wv.x * a0.z; acc[3] += wv.x * a0.w;
      acc[0] += wv.y * a1.x; acc[1] += wv.y * a1.y; acc[2] += wv.y * a1.z; acc[3] += wv.y * a1.w;
      acc[0] += wv.z * a2.x; acc[1] += wv.z * a2.y; acc[2] += wv.z * a2.z; acc[3] += wv.z * a2.w;
      acc[0] += wv.w * a3.x; acc[1] += wv.w * a3.y; acc[2] += wv.w * a3.z; acc[3] += wv.w * a3.w;
    }
    __syncthreads();
  }
  lred[rw][js] = lpart;
  __syncthreads();
  if (t < 16) {
    float s = 0.f;
#pragma unroll
    for (int q = 0; q < 16; ++q) s += lred[t][q];
    pl[(size_t)jh * NN + i0 + t] = s;
  }
#pragma unroll
  for (int oo = 0; oo < 4; ++oo) {
    int o = js * 4 + oo;
    if (o < H2DIM) pacc[((size_t)jh * NN + i0 + rw) * H2DIM + o] = acc[oo];
  }
}

__global__ __launch_bounds__(256) void k_att2c(const float* __restrict__ pacc, const float* __restrict__ pl,
                                               const float* __restrict__ b2, float* __restrict__ h2) {
  int n = blockIdx.x * 256 + threadIdx.x;
  if (n >= NN) return;
  float linv = 1.f / (pl[n] + pl[NN + n]);
  const float* pa = pacc + (size_t)n * H2DIM;
  const float* pb = pacc + (size_t)(NN + n) * H2DIM;
  float* ho = h2 + (size_t)n * H2DIM;
#pragma unroll
  for (int o = 0; o < H2DIM; ++o) ho[o] = lrelu((pa[o] + pb[o]) * linv + b2[o]);
}

// ---------------- FiLM + logits (one wave per node) ----------------
__global__ __launch_bounds__(64) void k_film(const float* __restrict__ l_loc, const float* __restrict__ h2,
                                             const float* __restrict__ Wl1, const float* __restrict__ bl1,
                                             const float* __restrict__ Wl2, const float* __restrict__ bl2,
                                             const float* __restrict__ Wg, const float* __restrict__ bg,
                                             const float* __restrict__ Wb, const float* __restrict__ bb,
                                             const float* __restrict__ Wgate, const float* __restrict__ bgate,
                                             const float* __restrict__ Wc, float* __restrict__ logits) {
  int n = blockIdx.x;
  int lane = threadIdx.x;
  __shared__ float z1s[32], z2s[32], loc_s[16];
  if (lane < 16) loc_s[lane] = l_loc[n * 16 + lane];
  __syncthreads();
  if (lane < 32) {
    float a = bl1[lane];
#pragma unroll
    for (int j = 0; j < 16; ++j) a += Wl1[lane * 16 + j] * loc_s[j];
    z1s[lane] = lrelu(a);
  }
  __syncthreads();
  if (lane < 32) {
    float a = bl2[lane];
#pragma unroll
    for (int j = 0; j < 32; ++j) a += Wl2[lane * 32 + j] * z1s[j];
    z2s[lane] = lrelu(a);
  }
  __syncthreads();
  float gs = bgate[0];
#pragma unroll
  for (int j = 0; j < 32; ++j) gs += Wgate[j] * z2s[j];
  float cov = loc_s[15];
  cov = cov < 0.f ? 0.f : (cov > 1.f ? 1.f : cov);
  float g = (1.f / (1.f + __expf(-gs))) * cov;
  float hf = 0.f;
  int o = lane;
  if (o < H2DIM) {
    float gam = bg[o], bet = bb[o];
#pragma unroll
    for (int j = 0; j < 32; ++j) {
      float z = z2s[j];
      gam += Wg[o * 32 + j] * z;
      bet += Wb[o * 32 + j] * z;
    }
    float hv = h2[(size_t)n * H2DIM + o];
    hf = hv + g * (gam * hv + bet);
  }
  float p0 = (o < H2DIM) ? hf * Wc[o] : 0.f;
  float p1 = (o < H2DIM) ? hf * Wc[H2DIM + o] : 0.f;
  for (int off = 32; off > 0; off >>= 1) {
    p0 += __shfl_down(p0, off);
    p1 += __shfl_down(p1, off);
  }
  if (lane == 0) {
    logits[n * 2 + 0] = lrelu(p0);
    logits[n * 2 + 1] = lrelu(p1);
  }
}

// ---------------- SSDB ----------------
// grid (8 n-chunks, 4 combos(hemi*2+c)), block 64
__global__ __launch_bounds__(64) void k_ssdb1(const float* __restrict__ logits, const float* __restrict__ Ws1,
                                              float* __restrict__ hsum) {
  int combo = blockIdx.y;
  int hemi = combo >> 1, c = combo & 1;
  int k = threadIdx.x;
  if (k >= 60) return;
  int nbase = blockIdx.x * 256;
  const float* wrow = Ws1 + (size_t)k * 2048 + nbase;
  const float* lcol = logits + (size_t)(hemi * 2048 + nbase) * 2 + c;
  float part = 0.f;
  for (int q = 0; q < 256; ++q) part += wrow[q] * lcol[2 * q];
  atomicAdd(&hsum[combo * 60 + k], part);
}

__global__ __launch_bounds__(256) void k_ssdb2(const float* __restrict__ hsum, const float* __restrict__ bs1,
                                               const float* __restrict__ Ws2, const float* __restrict__ bs2,
                                               float* __restrict__ B) {
  int t = threadIdx.x;
  int combo = t >> 6, k = t & 63;
  float part = 0.f;
  if (k < 60) part = lrelu(hsum[combo * 60 + k] + bs1[k]) * Ws2[k];
  for (int off = 32; off > 0; off >>= 1) part += __shfl_down(part, off);
  if (k == 0) B[combo] = lrelu(part + bs2[0]);
}

__global__ __launch_bounds__(256) void k_final(const float* __restrict__ logits, const float* __restrict__ B,
                                               float* __restrict__ out) {
  int id = blockIdx.x * 256 + threadIdx.x;
  if (id < 2 * NN) {
    int n = id >> 1, c = id & 1;
    out[id] = logits[id] + B[(n < 2048 ? 0 : 2) + c];
  } else if (id < 2 * NN + 2) {
    int c = id - 2 * NN;
    out[id] = 0.5f * (B[c] + B[2 + c]);
  }
}

// ---------------- workspace layout (float offsets) ----------------
#define OFF_P0 0                  // gemm1 partial z=0 (491520) ; later: PACC(409600)+PL(8192)
#define OFF_P1 491520             // gemm1 partial z=1 (491520) ; later: H2, LOG, HSUM, B
#define OFF_PACC 0
#define OFF_PL 409600
#define OFF_H2 491520
#define OFF_LOG 696320
#define OFF_HSUM 704512
#define OFF_B 704768
#define OFF_WH1 983040
#define OFF_F1A 1474560
#define OFF_F2A 1490944
#define OFF_MX1 1507328
#define OFF_H1 1507584
#define OFF_WH2 1999104
#define OFF_F12 2203904
#define OFF_F22 2208000
#define OFF_MX2 2212096
#define OFF_BITS 2212352          // u64 region: 4096*64 u64 = 524288 floats

extern "C" void kernel_launch(void* const* d_in, const int* in_sizes, int n_in,
                              void* d_out, int out_size, void* d_ws, size_t ws_size,
                              hipStream_t stream) {
  const float* x_fc  = (const float*)d_in[0];
  const int*   adj   = (const int*)d_in[1];
  const float* l_loc = (const float*)d_in[2];
  const float* W1    = (const float*)d_in[3];
  const float* a1s   = (const float*)d_in[4];
  const float* a1d   = (const float*)d_in[5];
  const float* b1    = (const float*)d_in[6];
  const float* W2    = (const float*)d_in[7];
  const float* a2s   = (const float*)d_in[8];
  const float* a2d   = (const float*)d_in[9];
  const float* b2    = (const float*)d_in[10];
  const float* Wc    = (const float*)d_in[11];
  const float* Wl1   = (const float*)d_in[12];
  const float* bl1   = (const float*)d_in[13];
  const float* Wl2   = (const float*)d_in[14];
  const float* bl2   = (const float*)d_in[15];
  const float* Wg    = (const float*)d_in[16];
  const float* bg    = (const float*)d_in[17];
  const float* Wb    = (const float*)d_in[18];
  const float* bb    = (const float*)d_in[19];
  const float* Wgate = (const float*)d_in[20];
  const float* bgate = (const float*)d_in[21];
  const float* Ws1   = (const float*)d_in[22];
  const float* bs1   = (const float*)d_in[23];
  const float* Ws2   = (const float*)d_in[24];
  const float* bs2   = (const float*)d_in[25];
  float* out = (float*)d_out;
  float* w = (float*)d_ws;
  unsigned long long* bits = (unsigned long long*)(w + OFF_BITS);

  // 1. bitmask
  k_bits<<<NN * NN / 256, 256, 0, stream>>>(adj, bits);
  // 2. wh1 partials
  k_gemm1<<<dim3(64, HEADS, 2), 256, 0, stream>>>(x_fc, W1, w + OFF_P0);
  // 3. combine + f1/f2
  k_f1<<<(HEADS * NN) / 256, 256, 0, stream>>>(w + OFF_P0, w + OFF_P1, a1s, a1d,
                                               w + OFF_WH1, w + OFF_F1A, w + OFF_F2A);
  // 4. per-head max f2
  k_max<<<HEADS, 256, 0, stream>>>(w + OFF_F2A, w + OFF_MX1);
  // 5. fused attention layer 1 -> h1
  k_att1<<<dim3(128, HEADS), 256, 0, stream>>>(w + OFF_WH1, w + OFF_F1A, w + OFF_F2A,
                                               w + OFF_MX1, bits, b1, w + OFF_H1);
  // 6. wh2
  k_gemm2<<<NN / 4, 256, 0, stream>>>(w + OFF_H1, W2, w + OFF_WH2);
  // 7. layer-2 f1/f2
  k_f2l2<<<NN / 256, 256, 0, stream>>>(w + OFF_WH2, a2s, a2d, w + OFF_F12, w + OFF_F22);
  // 8. max f22
  k_max<<<1, 256, 0, stream>>>(w + OFF_F22, w + OFF_MX2);
  // 9. fused attention layer 2 (j-split partials)
  k_att2<<<dim3(256, 2), 256, 0, stream>>>(w + OFF_WH2, w + OFF_F12, w + OFF_F22,
                                           w + OFF_MX2, bits, w + OFF_PACC, w + OFF_PL);
  // 10. combine -> h2
  k_att2c<<<NN / 256, 256, 0, stream>>>(w + OFF_PACC, w + OFF_PL, b2, w + OFF_H2);
  // 11. FiLM + logits (pre-bias)
  k_film<<<NN, 64, 0, stream>>>(l_loc, w + OFF_H2, Wl1, bl1, Wl2, bl2, Wg, bg, Wb, bb,
                                Wgate, bgate, Wc, w + OFF_LOG);
  // 12. SSDB
  hipMemsetAsync(w + OFF_HSUM, 0, 240 * sizeof(float), stream);
  k_ssdb1<<<dim3(8, 4), 64, 0, stream>>>(w + OFF_LOG, Ws1, w + OFF_HSUM);
  k_ssdb2<<<1, 256, 0, stream>>>(w + OFF_HSUM, bs1, Ws2, bs2, w + OFF_B);
  // 13. finalize outputs
  k_final<<<(2 * NN + 2 + 255) / 256, 256, 0, stream>>>(w + OFF_LOG, w + OFF_B, out);
}

// Round 2
// 468.398 us; speedup vs baseline: 1.7124x; 1.7124x over previous
//
#include <hip/hip_runtime.h>

#define NN 4096
#define HEADS 4
#define H1PER 30
#define H1DIM 120
#define H2DIM 50

typedef short short8_t __attribute__((ext_vector_type(8)));
typedef float f32x4 __attribute__((ext_vector_type(4)));

__device__ __forceinline__ float lrelu(float x) { return x > 0.f ? x : 0.1f * x; }

// round-to-nearest-even float->bf16 (for stored wh tiles)
__device__ __forceinline__ unsigned short bfrne(float x) {
  unsigned u = __float_as_uint(x);
  u += 0x7fffu + ((u >> 16) & 1u);
  return (unsigned short)(u >> 16);
}
// pack two floats to bf16x2 (round-half-up; wv>=0, tiny bias cancels via l-normalization)
__device__ __forceinline__ unsigned bfpk(float lo, float hi) {
  unsigned a = (__float_as_uint(lo) + 0x8000u) >> 16;
  unsigned b = (__float_as_uint(hi) + 0x8000u) & 0xffff0000u;
  return a | b;
}
// alpha-weight: exp(lrelu(f1+f2) - m) * maskbit
__device__ __forceinline__ float score(float f2v, float f1r, float mr, unsigned bsel, int jj) {
  float f = f1r + f2v;
  float e = fmaxf(f, 0.1f * f);
  float wv = __expf(e - mr);
  return wv * (float)((bsel >> jj) & 1u);
}

// ---------------- bitmask: adj(int32) -> 1 bit ----------------
__global__ __launch_bounds__(256) void k_bits(const int* __restrict__ adj,
                                              unsigned long long* __restrict__ bits) {
  int e = blockIdx.x * 256 + threadIdx.x;
  unsigned long long m = __ballot(adj[e] > 0);
  if ((threadIdx.x & 63) == 0) bits[e >> 6] = m;
}

// ---------------- GEMM1: partial wh1 = x @ W1 (K-split 2) ----------------
__global__ __launch_bounds__(256) void k_gemm1(const float* __restrict__ x,
                                               const float* __restrict__ W1,
                                               float* __restrict__ part) {
  const int h = blockIdx.y, z = blockIdx.z;
  const int i0 = blockIdx.x * 64;
  const int t = threadIdx.x;
  const int o = t & 31, rg = t >> 5;
  __shared__ float xs[64][68];
  __shared__ float wt[64][32];
  float acc[8];
#pragma unroll
  for (int q = 0; q < 8; ++q) acc[q] = 0.f;
  const int r_ld = t >> 2;
  const int kb_ld = (t & 3) * 16;
  float* pz = part + (size_t)z * (HEADS * NN * H1PER);
  for (int kc = z * 2048; kc < z * 2048 + 2048; kc += 64) {
    const float* xp = x + (size_t)(i0 + r_ld) * 4096 + kc + kb_ld;
#pragma unroll
    for (int v = 0; v < 4; ++v) {
      float4 xv = *(const float4*)(xp + v * 4);
      xs[kb_ld + v * 4 + 0][r_ld] = xv.x;
      xs[kb_ld + v * 4 + 1][r_ld] = xv.y;
      xs[kb_ld + v * 4 + 2][r_ld] = xv.z;
      xs[kb_ld + v * 4 + 3][r_ld] = xv.w;
    }
    const float* wp = W1 + (size_t)(h * 4096 + kc) * H1PER;
    for (int e = t; e < 64 * H1PER; e += 256) wt[e / H1PER][e % H1PER] = wp[e];
    __syncthreads();
#pragma unroll 4
    for (int kk = 0; kk < 64; ++kk) {
      float wv = wt[kk][o];
      const float4 xa = *(const float4*)&xs[kk][rg * 8];
      const float4 xb = *(const float4*)&xs[kk][rg * 8 + 4];
      acc[0] += xa.x * wv; acc[1] += xa.y * wv; acc[2] += xa.z * wv; acc[3] += xa.w * wv;
      acc[4] += xb.x * wv; acc[5] += xb.y * wv; acc[6] += xb.z * wv; acc[7] += xb.w * wv;
    }
    __syncthreads();
  }
  if (o < H1PER) {
    float* pp = pz + ((size_t)h * NN + i0) * H1PER;
#pragma unroll
    for (int q = 0; q < 8; ++q) pp[(rg * 8 + q) * H1PER + o] = acc[q];
  }
}

// ---------------- combine partials + f1/f2 + bf16 wh1^T (padded, ones col) ----------------
__global__ __launch_bounds__(256) void k_f1(const float* __restrict__ p0, const float* __restrict__ p1,
                                            const float* __restrict__ a1s, const float* __restrict__ a1d,
                                            unsigned short* __restrict__ whbt, float* __restrict__ f1,
                                            float* __restrict__ f2) {
  int id = blockIdx.x * 256 + threadIdx.x;  // h*4096+n
  if (id >= HEADS * NN) return;
  int h = id >> 12, n = id & 4095;
  const float* s = a1s + h * H1PER;
  const float* dv = a1d + h * H1PER;
  const float* q0 = p0 + (size_t)id * H1PER;
  const float* q1 = p1 + (size_t)id * H1PER;
  unsigned short* wb = whbt + (size_t)h * 32 * NN + n;
  float accs = 0.f, accd = 0.f;
#pragma unroll
  for (int j = 0; j < H1PER; ++j) {
    float v = q0[j] + q1[j];
    wb[j * NN] = bfrne(v);
    accs += v * s[j];
    accd += v * dv[j];
  }
  wb[30 * NN] = 0x3f80;  // 1.0 -> denominator column
  wb[31 * NN] = 0;
  f1[id] = accs;
  f2[id] = accd;
}

// ---------------- per-row max over 4096 values ----------------
__global__ __launch_bounds__(256) void k_max(const float* __restrict__ v, float* __restrict__ mx) {
  int t = threadIdx.x;
  const float* row = v + (size_t)blockIdx.x * NN;
  float m = -3.0e38f;
  for (int n = t; n < NN; n += 256) m = fmaxf(m, row[n]);
  for (int off = 32; off > 0; off >>= 1) m = fmaxf(m, __shfl_down(m, off));
  __shared__ float ms[4];
  if ((t & 63) == 0) ms[t >> 6] = m;
  __syncthreads();
  if (t == 0) mx[blockIdx.x] = fmaxf(fmaxf(ms[0], ms[1]), fmaxf(ms[2], ms[3]));
}

// ---------------- MFMA attention layer 1 ----------------
// grid (64 i-blocks, 4 heads, 2 j-split), block 256 (4 waves x 16 rows)
__global__ __launch_bounds__(256) void k_att1m(const unsigned short* __restrict__ whbt,
                                               const float* __restrict__ f1, const float* __restrict__ f2,
                                               const float* __restrict__ mx,
                                               const unsigned int* __restrict__ bits32,
                                               float* __restrict__ part) {
  const int h = blockIdx.y, js = blockIdx.z;
  const int t = threadIdx.x;
  const int lane = t & 63, wave = t >> 6;
  const int m = lane & 15, q = lane >> 4;
  const int i0 = blockIdx.x * 64 + wave * 16;
  const int jbase = js * 2048;
  __shared__ float f2s[2048];
  for (int e = t; e < 2048; e += 256) f2s[e] = f2[h * NN + jbase + e];
  __syncthreads();
  const float f1r = f1[h * NN + i0 + m];
  const float fm = f1r + mx[h];
  const float mr = fmaxf(fm, 0.1f * fm);
  const unsigned int* brow = bits32 + (size_t)(i0 + m) * 128 + (jbase >> 5);
  const unsigned short* bb0 = whbt + (size_t)(h * 32 + m) * NN + jbase + q * 8;
  const unsigned short* bb1 = bb0 + 16 * NN;
  const float* fp = f2s + q * 8;
  f32x4 acc0 = {0.f, 0.f, 0.f, 0.f}, acc1 = {0.f, 0.f, 0.f, 0.f};
  for (int step = 0; step < 64; ++step) {
    const int jl = step * 32;
    unsigned bsel = brow[step] >> (q * 8);
    float4 fa = *(const float4*)(fp + jl);
    float4 fb = *(const float4*)(fp + jl + 4);
    float w0 = score(fa.x, f1r, mr, bsel, 0);
    float w1 = score(fa.y, f1r, mr, bsel, 1);
    float w2 = score(fa.z, f1r, mr, bsel, 2);
    float w3 = score(fa.w, f1r, mr, bsel, 3);
    float w4 = score(fb.x, f1r, mr, bsel, 4);
    float w5 = score(fb.y, f1r, mr, bsel, 5);
    float w6 = score(fb.z, f1r, mr, bsel, 6);
    float w7 = score(fb.w, f1r, mr, bsel, 7);
    union { short8_t v; unsigned u[4]; } A;
    A.u[0] = bfpk(w0, w1);
    A.u[1] = bfpk(w2, w3);
    A.u[2] = bfpk(w4, w5);
    A.u[3] = bfpk(w6, w7);
    short8_t b0 = *(const short8_t*)(bb0 + jl);
    short8_t b1 = *(const short8_t*)(bb1 + jl);
    acc0 = __builtin_amdgcn_mfma_f32_16x16x32_bf16(A.v, b0, acc0, 0, 0, 0);
    acc1 = __builtin_amdgcn_mfma_f32_16x16x32_bf16(A.v, b1, acc1, 0, 0, 0);
  }
  // C/D layout: row = q*4+reg, col = m
  float* pp = part + ((size_t)(js * 4 + h) * NN + i0 + q * 4) * 32 + m;
#pragma unroll
  for (int r = 0; r < 4; ++r) {
    pp[r * 32] = acc0[r];
    pp[r * 32 + 16] = acc1[r];
  }
}

// ---------------- combine layer-1 partials -> h1 ----------------
// grid 8192, block 64: two (h,n) pairs per wave, lane = p*32+o
__global__ __launch_bounds__(64) void k_h1(const float* __restrict__ part, const float* __restrict__ b1,
                                           float* __restrict__ h1) {
  int lane = threadIdx.x;
  int p = lane >> 5, o = lane & 31;
  int id = blockIdx.x * 2 + p;  // h*4096+n
  int h = id >> 12, n = id & 4095;
  const float* p0 = part + ((size_t)h * NN + n) * 32 + o;
  const float* p1 = part + ((size_t)(4 + h) * NN + n) * 32 + o;
  float tot = p0[0] + p1[0];
  float l = __shfl(tot, p * 32 + 30);
  if (o < H1PER) h1[(size_t)n * H1DIM + h * H1PER + o] = lrelu(tot / l + b1[h * H1PER + o]);
}

// ---------------- GEMM2: wh2 = h1 @ W2 ----------------
__global__ __launch_bounds__(256) void k_gemm2(const float* __restrict__ h1, const float* __restrict__ W2,
                                               float* __restrict__ wh2) {
  const int n0 = blockIdx.x * 4;
  const int t = threadIdx.x;
  const int o = t & 63, r = t >> 6;
  __shared__ float hs[4][120];
  for (int e = t; e < 4 * H1DIM; e += 256) hs[e / H1DIM][e % H1DIM] = h1[(size_t)n0 * H1DIM + e];
  __syncthreads();
  if (o < H2DIM) {
    float acc = 0.f;
#pragma unroll 4
    for (int k = 0; k < H1DIM; ++k) acc += hs[r][k] * W2[k * H2DIM + o];
    wh2[(size_t)(n0 + r) * H2DIM + o] = acc;
  }
}

// ---------------- layer-2 f1/f2 + bf16 wh2^T (padded to 64, ones col at 50) ----------------
__global__ __launch_bounds__(256) void k_f2l2(const float* __restrict__ wh2, const float* __restrict__ a2s,
                                              const float* __restrict__ a2d, float* __restrict__ f1,
                                              float* __restrict__ f2, unsigned short* __restrict__ whbt) {
  int n = blockIdx.x * 256 + threadIdx.x;
  if (n >= NN) return;
  const float* r = wh2 + (size_t)n * H2DIM;
  unsigned short* wb = whbt + n;
  float accs = 0.f, accd = 0.f;
#pragma unroll
  for (int j = 0; j < H2DIM; ++j) {
    float v = r[j];
    wb[j * NN] = bfrne(v);
    accs += v * a2s[j];
    accd += v * a2d[j];
  }
  wb[50 * NN] = 0x3f80;  // 1.0 -> denominator column
#pragma unroll
  for (int j = 51; j < 64; ++j) wb[j * NN] = 0;
  f1[n] = accs;
  f2[n] = accd;
}

// ---------------- MFMA attention layer 2 ----------------
// grid (64 i-blocks, 4 j-split), block 256
__global__ __launch_bounds__(256) void k_att2m(const unsigned short* __restrict__ whbt,
                                               const float* __restrict__ f1, const float* __restrict__ f2,
                                               const float* __restrict__ mx,
                                               const unsigned int* __restrict__ bits32,
                                               float* __restrict__ part) {
  const int js = blockIdx.y;
  const int t = threadIdx.x;
  const int lane = t & 63, wave = t >> 6;
  const int m = lane & 15, q = lane >> 4;
  const int i0 = blockIdx.x * 64 + wave * 16;
  const int jbase = js * 1024;
  __shared__ float f2s[1024];
  for (int e = t; e < 1024; e += 256) f2s[e] = f2[jbase + e];
  __syncthreads();
  const float f1r = f1[i0 + m];
  const float fm = f1r + mx[0];
  const float mr = fmaxf(fm, 0.1f * fm);
  const unsigned int* brow = bits32 + (size_t)(i0 + m) * 128 + (jbase >> 5);
  const unsigned short* bb = whbt + (size_t)m * NN + jbase + q * 8;
  const float* fp = f2s + q * 8;
  f32x4 acc[4];
#pragma unroll
  for (int x = 0; x < 4; ++x) acc[x] = (f32x4){0.f, 0.f, 0.f, 0.f};
  for (int step = 0; step < 32; ++step) {
    const int jl = step * 32;
    unsigned bsel = brow[step] >> (q * 8);
    float4 fa = *(const float4*)(fp + jl);
    float4 fb = *(const float4*)(fp + jl + 4);
    float w0 = score(fa.x, f1r, mr, bsel, 0);
    float w1 = score(fa.y, f1r, mr, bsel, 1);
    float w2 = score(fa.z, f1r, mr, bsel, 2);
    float w3 = score(fa.w, f1r, mr, bsel, 3);
    float w4 = score(fb.x, f1r, mr, bsel, 4);
    float w5 = score(fb.y, f1r, mr, bsel, 5);
    float w6 = score(fb.z, f1r, mr, bsel, 6);
    float w7 = score(fb.w, f1r, mr, bsel, 7);
    union { short8_t v; unsigned u[4]; } A;
    A.u[0] = bfpk(w0, w1);
    A.u[1] = bfpk(w2, w3);
    A.u[2] = bfpk(w4, w5);
    A.u[3] = bfpk(w6, w7);
#pragma unroll
    for (int tile = 0; tile < 4; ++tile) {
      short8_t b = *(const short8_t*)(bb + (size_t)tile * 16 * NN + jl);
      acc[tile] = __builtin_amdgcn_mfma_f32_16x16x32_bf16(A.v, b, acc[tile], 0, 0, 0);
    }
  }
  float* pp = part + ((size_t)js * NN + i0 + q * 4) * 64 + m;
#pragma unroll
  for (int tile = 0; tile < 4; ++tile)
#pragma unroll
    for (int r = 0; r < 4; ++r) pp[r * 64 + tile * 16] = acc[tile][r];
}

// ---------------- combine layer-2 partials -> h2 ----------------
// grid 4096, block 64: one node per wave, lane = o
__global__ __launch_bounds__(64) void k_h2(const float* __restrict__ part, const float* __restrict__ b2,
                                           float* __restrict__ h2) {
  int n = blockIdx.x;
  int o = threadIdx.x;
  const float* p = part + (size_t)n * 64 + o;
  float tot = p[0] + p[NN * 64] + p[2 * NN * 64] + p[3 * NN * 64];
  float l = __shfl(tot, 50);
  if (o < H2DIM) h2[(size_t)n * H2DIM + o] = lrelu(tot / l + b2[o]);
}

// ---------------- FiLM + logits (one wave per node) ----------------
__global__ __launch_bounds__(64) void k_film(const float* __restrict__ l_loc, const float* __restrict__ h2,
                                             const float* __restrict__ Wl1, const float* __restrict__ bl1,
                                             const float* __restrict__ Wl2, const float* __restrict__ bl2,
                                             const float* __restrict__ Wg, const float* __restrict__ bg,
                                             const float* __restrict__ Wb, const float* __restrict__ bb,
                                             const float* __restrict__ Wgate, const float* __restrict__ bgate,
                                             const float* __restrict__ Wc, float* __restrict__ logits) {
  int n = blockIdx.x;
  int lane = threadIdx.x;
  __shared__ float z1s[32], z2s[32], loc_s[16];
  if (lane < 16) loc_s[lane] = l_loc[n * 16 + lane];
  __syncthreads();
  if (lane < 32) {
    float a = bl1[lane];
#pragma unroll
    for (int j = 0; j < 16; ++j) a += Wl1[lane * 16 + j] * loc_s[j];
    z1s[lane] = lrelu(a);
  }
  __syncthreads();
  if (lane < 32) {
    float a = bl2[lane];
#pragma unroll
    for (int j = 0; j < 32; ++j) a += Wl2[lane * 32 + j] * z1s[j];
    z2s[lane] = lrelu(a);
  }
  __syncthreads();
  float gs = bgate[0];
#pragma unroll
  for (int j = 0; j < 32; ++j) gs += Wgate[j] * z2s[j];
  float cov = loc_s[15];
  cov = cov < 0.f ? 0.f : (cov > 1.f ? 1.f : cov);
  float g = (1.f / (1.f + __expf(-gs))) * cov;
  float hf = 0.f;
  int o = lane;
  if (o < H2DIM) {
    float gam = bg[o], bet = bb[o];
#pragma unroll
    for (int j = 0; j < 32; ++j) {
      float z = z2s[j];
      gam += Wg[o * 32 + j] * z;
      bet += Wb[o * 32 + j] * z;
    }
    float hv = h2[(size_t)n * H2DIM + o];
    hf = hv + g * (gam * hv + bet);
  }
  float p0 = (o < H2DIM) ? hf * Wc[o] : 0.f;
  float p1 = (o < H2DIM) ? hf * Wc[H2DIM + o] : 0.f;
  for (int off = 32; off > 0; off >>= 1) {
    p0 += __shfl_down(p0, off);
    p1 += __shfl_down(p1, off);
  }
  if (lane == 0) {
    logits[n * 2 + 0] = lrelu(p0);
    logits[n * 2 + 1] = lrelu(p1);
  }
}

// ---------------- SSDB ----------------
__global__ __launch_bounds__(64) void k_ssdb1(const float* __restrict__ logits, const float* __restrict__ Ws1,
                                              float* __restrict__ hsum) {
  int combo = blockIdx.y;
  int hemi = combo >> 1, c = combo & 1;
  int k = threadIdx.x;
  if (k >= 60) return;
  int nbase = blockIdx.x * 256;
  const float* wrow = Ws1 + (size_t)k * 2048 + nbase;
  const float* lcol = logits + (size_t)(hemi * 2048 + nbase) * 2 + c;
  float part = 0.f;
  for (int q = 0; q < 256; ++q) part += wrow[q] * lcol[2 * q];
  atomicAdd(&hsum[combo * 60 + k], part);
}

__global__ __launch_bounds__(256) void k_ssdb2(const float* __restrict__ hsum, const float* __restrict__ bs1,
                                               const float* __restrict__ Ws2, const float* __restrict__ bs2,
                                               float* __restrict__ B) {
  int t = threadIdx.x;
  int combo = t >> 6, k = t & 63;
  float part = 0.f;
  if (k < 60) part = lrelu(hsum[combo * 60 + k] + bs1[k]) * Ws2[k];
  for (int off = 32; off > 0; off >>= 1) part += __shfl_down(part, off);
  if (k == 0) B[combo] = lrelu(part + bs2[0]);
}

__global__ __launch_bounds__(256) void k_final(const float* __restrict__ logits, const float* __restrict__ B,
                                               float* __restrict__ out) {
  int id = blockIdx.x * 256 + threadIdx.x;
  if (id < 2 * NN) {
    int n = id >> 1, c = id & 1;
    out[id] = logits[id] + B[(n < 2048 ? 0 : 2) + c];
  } else if (id < 2 * NN + 2) {
    int c = id - 2 * NN;
    out[id] = 0.5f * (B[c] + B[2 + c]);
  }
}

// ---------------- workspace layout (float offsets) ----------------
#define OFF_BITS 0          // 524288 f (u64 bitmask 4096x4096)
#define OFF_WH1BT 524288    // 262144 f (bf16 [h][32][4096])
#define OFF_P0 786432       // 491520 f (gemm1 partial z=0; dead after k_f1)
#define OFF_P1 1277952      // 491520 f (z=1)
#define OFF_A1P 786432      // 1048576 f (att1 partials [2][4][4096][32]; overlays P)
#define OFF_F1A 1835008     // 16384
#define OFF_F2A 1851392     // 16384
#define OFF_MX1 1867776     // 64
#define OFF_H1 1867840      // 491520
#define OFF_WH2 2359360     // 204800
#define OFF_WH2BT 2564160   // 131072 f (bf16 [64][4096])
#define OFF_F12 2695232     // 4096
#define OFF_F22 2699328     // 4096
#define OFF_MX2 2703424     // 64
#define OFF_A2P 524288      // 1048576 f (att2 partials [4][4096][64]; overlays WH1BT+A1P)
#define OFF_H2 2703488      // 204800
#define OFF_LOG 2908288     // 8192
#define OFF_HSUM 2916480    // 256
#define OFF_B 2916736       // 8

extern "C" void kernel_launch(void* const* d_in, const int* in_sizes, int n_in,
                              void* d_out, int out_size, void* d_ws, size_t ws_size,
                              hipStream_t stream) {
  const float* x_fc  = (const float*)d_in[0];
  const int*   adj   = (const int*)d_in[1];
  const float* l_loc = (const float*)d_in[2];
  const float* W1    = (const float*)d_in[3];
  const float* a1s   = (const float*)d_in[4];
  const float* a1d   = (const float*)d_in[5];
  const float* b1    = (const float*)d_in[6];
  const float* W2    = (const float*)d_in[7];
  const float* a2s   = (const float*)d_in[8];
  const float* a2d   = (const float*)d_in[9];
  const float* b2    = (const float*)d_in[10];
  const float* Wc    = (const float*)d_in[11];
  const float* Wl1   = (const float*)d_in[12];
  const float* bl1   = (const float*)d_in[13];
  const float* Wl2   = (const float*)d_in[14];
  const float* bl2   = (const float*)d_in[15];
  const float* Wg    = (const float*)d_in[16];
  const float* bg    = (const float*)d_in[17];
  const float* Wb    = (const float*)d_in[18];
  const float* bb    = (const float*)d_in[19];
  const float* Wgate = (const float*)d_in[20];
  const float* bgate = (const float*)d_in[21];
  const float* Ws1   = (const float*)d_in[22];
  const float* bs1   = (const float*)d_in[23];
  const float* Ws2   = (const float*)d_in[24];
  const float* bs2   = (const float*)d_in[25];
  float* out = (float*)d_out;
  float* w = (float*)d_ws;
  unsigned long long* bits = (unsigned long long*)(w + OFF_BITS);
  const unsigned int* bits32 = (const unsigned int*)bits;
  unsigned short* wh1bt = (unsigned short*)(w + OFF_WH1BT);
  unsigned short* wh2bt = (unsigned short*)(w + OFF_WH2BT);

  k_bits<<<NN * NN / 256, 256, 0, stream>>>(adj, bits);
  k_gemm1<<<dim3(64, HEADS, 2), 256, 0, stream>>>(x_fc, W1, w + OFF_P0);
  k_f1<<<(HEADS * NN) / 256, 256, 0, stream>>>(w + OFF_P0, w + OFF_P1, a1s, a1d,
                                               wh1bt, w + OFF_F1A, w + OFF_F2A);
  k_max<<<HEADS, 256, 0, stream>>>(w + OFF_F2A, w + OFF_MX1);
  k_att1m<<<dim3(64, HEADS, 2), 256, 0, stream>>>(wh1bt, w + OFF_F1A, w + OFF_F2A,
                                                  w + OFF_MX1, bits32, w + OFF_A1P);
  k_h1<<<8192, 64, 0, stream>>>(w + OFF_A1P, b1, w + OFF_H1);
  k_gemm2<<<NN / 4, 256, 0, stream>>>(w + OFF_H1, W2, w + OFF_WH2);
  k_f2l2<<<NN / 256, 256, 0, stream>>>(w + OFF_WH2, a2s, a2d, w + OFF_F12, w + OFF_F22, wh2bt);
  k_max<<<1, 256, 0, stream>>>(w + OFF_F22, w + OFF_MX2);
  k_att2m<<<dim3(64, 4), 256, 0, stream>>>(wh2bt, w + OFF_F12, w + OFF_F22,
                                           w + OFF_MX2, bits32, w + OFF_A2P);
  k_h2<<<NN, 64, 0, stream>>>(w + OFF_A2P, b2, w + OFF_H2);
  k_film<<<NN, 64, 0, stream>>>(l_loc, w + OFF_H2, Wl1, bl1, Wl2, bl2, Wg, bg, Wb, bb,
                                Wgate, bgate, Wc, w + OFF_LOG);
  hipMemsetAsync(w + OFF_HSUM, 0, 240 * sizeof(float), stream);
  k_ssdb1<<<dim3(8, 4), 64, 0, stream>>>(w + OFF_LOG, Ws1, w + OFF_HSUM);
  k_ssdb2<<<1, 256, 0, stream>>>(w + OFF_HSUM, bs1, Ws2, bs2, w + OFF_B);
  k_final<<<(2 * NN + 2 + 255) / 256, 256, 0, stream>>>(w + OFF_LOG, w + OFF_B, out);
}

// Round 3
// 385.460 us; speedup vs baseline: 2.0808x; 1.2152x over previous
//
#include <hip/hip_runtime.h>

#define NN 4096
#define HEADS 4
#define H1PER 30
#define H1DIM 120
#define H2DIM 50

typedef short short8_t __attribute__((ext_vector_type(8)));
typedef float f32x4 __attribute__((ext_vector_type(4)));

__device__ __forceinline__ float lrelu(float x) { return x > 0.f ? x : 0.1f * x; }

// round-to-nearest-even float->bf16
__device__ __forceinline__ unsigned short bfrne(float x) {
  unsigned u = __float_as_uint(x);
  u += 0x7fffu + ((u >> 16) & 1u);
  return (unsigned short)(u >> 16);
}
__device__ __forceinline__ unsigned bfpk_rne(float lo, float hi) {
  return (unsigned)bfrne(lo) | ((unsigned)bfrne(hi) << 16);
}
// pack two floats to bf16x2 (round-half-up; for nonneg alpha weights)
__device__ __forceinline__ unsigned bfpk(float lo, float hi) {
  unsigned a = (__float_as_uint(lo) + 0x8000u) >> 16;
  unsigned b = (__float_as_uint(hi) + 0x8000u) & 0xffff0000u;
  return a | b;
}
// alpha-weight: exp(lrelu(f1+f2) - m) * maskbit
__device__ __forceinline__ float score(float f2v, float f1r, float mr, unsigned bsel, int jj) {
  float f = f1r + f2v;
  float e = fmaxf(f, 0.1f * f);
  float wv = __expf(e - mr);
  return wv * (float)((bsel >> jj) & 1u);
}

// ---------------- bitmask: adj(int32) -> 1 bit ----------------
__global__ __launch_bounds__(256) void k_bits(const int* __restrict__ adj,
                                              unsigned long long* __restrict__ bits) {
  int e = blockIdx.x * 256 + threadIdx.x;
  unsigned long long m = __ballot(adj[e] > 0);
  if ((threadIdx.x & 63) == 0) bits[e >> 6] = m;
}

// ---------------- prep: W1 -> bf16 w1t[128][4096]; cols 120..127 = f1/f2 features ----------------
__global__ __launch_bounds__(256) void k_prep(const float* __restrict__ W1,
                                              const float* __restrict__ a1s,
                                              const float* __restrict__ a1d,
                                              unsigned short* __restrict__ w1t) {
  int k = blockIdx.x * 256 + threadIdx.x;  // 0..4095
#pragma unroll
  for (int h = 0; h < 4; ++h) {
    const float* wp = W1 + ((size_t)h * 4096 + k) * H1PER;
    float fs = 0.f, fd = 0.f;
#pragma unroll
    for (int oo = 0; oo < H1PER; ++oo) {
      float v = wp[oo];
      w1t[(size_t)(h * 30 + oo) * 4096 + k] = bfrne(v);
      fs += v * a1s[h * H1PER + oo];
      fd += v * a1d[h * H1PER + oo];
    }
    w1t[(size_t)(120 + h) * 4096 + k] = bfrne(fs);
    w1t[(size_t)(124 + h) * 4096 + k] = bfrne(fd);
  }
}

// ---------------- MFMA GEMM1: part[z] = x[:, z*512:+512] @ w1t^T ----------------
// grid (64 mblocks, 8 ksplit), block 256 (4 waves; wave = one 16-row m-tile x 128 cols)
__global__ __launch_bounds__(256) void k_gemm1s(const float* __restrict__ x,
                                                const unsigned short* __restrict__ w1t,
                                                float* __restrict__ part) {
  const int t = threadIdx.x;
  const int lane = t & 63, wave = t >> 6;
  const int m = lane & 15, q = lane >> 4;
  const int i0 = blockIdx.x * 64;
  const int kz = blockIdx.y * 512;
  __shared__ float xs[64][68];
  f32x4 acc[8];
#pragma unroll
  for (int nt = 0; nt < 8; ++nt) acc[nt] = (f32x4){0.f, 0.f, 0.f, 0.f};
  const int r_ld = t >> 2;
  const int c_ld = (t & 3) * 16;
  const unsigned short* wb = w1t + (size_t)m * 4096;
  for (int kc = kz; kc < kz + 512; kc += 64) {
    const float* xp = x + (size_t)(i0 + r_ld) * 4096 + kc + c_ld;
    float4 v0 = *(const float4*)(xp);
    float4 v1 = *(const float4*)(xp + 4);
    float4 v2 = *(const float4*)(xp + 8);
    float4 v3 = *(const float4*)(xp + 12);
    __syncthreads();
    *(float4*)&xs[r_ld][c_ld] = v0;
    *(float4*)&xs[r_ld][c_ld + 4] = v1;
    *(float4*)&xs[r_ld][c_ld + 8] = v2;
    *(float4*)&xs[r_ld][c_ld + 12] = v3;
    __syncthreads();
#pragma unroll
    for (int ks = 0; ks < 2; ++ks) {
      const int kk = ks * 32 + q * 8;
      const float* xr = &xs[wave * 16 + m][kk];
      float4 a0 = *(const float4*)(xr);
      float4 a1 = *(const float4*)(xr + 4);
      union { short8_t v; unsigned u[4]; } A;
      A.u[0] = bfpk_rne(a0.x, a0.y);
      A.u[1] = bfpk_rne(a0.z, a0.w);
      A.u[2] = bfpk_rne(a1.x, a1.y);
      A.u[3] = bfpk_rne(a1.z, a1.w);
      const unsigned short* wp = wb + kc + kk;
#pragma unroll
      for (int nt = 0; nt < 8; ++nt) {
        short8_t B = *(const short8_t*)(wp + (size_t)nt * 16 * 4096);
        acc[nt] = __builtin_amdgcn_mfma_f32_16x16x32_bf16(A.v, B, acc[nt], 0, 0, 0);
      }
    }
  }
  // C/D: row = q*4+reg, col = m (per 16-col n-tile)
  float* pp = part + ((size_t)blockIdx.y * 4096 + i0 + wave * 16 + q * 4) * 128 + m;
#pragma unroll
  for (int nt = 0; nt < 8; ++nt)
#pragma unroll
    for (int r = 0; r < 4; ++r) pp[r * 128 + nt * 16] = acc[nt][r];
}

// ---------------- combine k-split partials -> whbt(bf16,T) + f1/f2 ----------------
// grid 256 blocks, 256 threads: 16 nodes/block, 16 threads/node (8 cols each)
__global__ __launch_bounds__(256) void k_f1c(const float* __restrict__ part,
                                             unsigned short* __restrict__ whbt,
                                             float* __restrict__ f1, float* __restrict__ f2) {
  const int t = threadIdx.x;
  const int n = blockIdx.x * 16 + (t >> 4);
  const int og = (t & 15) * 8;
  float s[8] = {0.f, 0.f, 0.f, 0.f, 0.f, 0.f, 0.f, 0.f};
  for (int z = 0; z < 8; ++z) {
    const float* pp = part + ((size_t)z * NN + n) * 128 + og;
    float4 u0 = *(const float4*)pp;
    float4 u1 = *(const float4*)(pp + 4);
    s[0] += u0.x; s[1] += u0.y; s[2] += u0.z; s[3] += u0.w;
    s[4] += u1.x; s[5] += u1.y; s[6] += u1.z; s[7] += u1.w;
  }
  if (og < 120) {
#pragma unroll
    for (int j = 0; j < 8; ++j) {
      int o = og + j;
      int h = o / 30, oo = o - h * 30;
      whbt[(size_t)(h * 32 + oo) * NN + n] = bfrne(s[j]);
    }
  } else {
#pragma unroll
    for (int j = 0; j < 4; ++j) {
      f1[(size_t)j * NN + n] = s[j];
      f2[(size_t)j * NN + n] = s[4 + j];
    }
  }
  if ((t & 15) < 8) {
    int h = (t & 15) >> 1, odd = (t & 15) & 1;
    whbt[(size_t)(h * 32 + 30 + odd) * NN + n] = odd ? 0 : 0x3f80;
  }
}

// ---------------- per-row max over 4096 values ----------------
__global__ __launch_bounds__(256) void k_max(const float* __restrict__ v, float* __restrict__ mx) {
  int t = threadIdx.x;
  const float* row = v + (size_t)blockIdx.x * NN;
  float m = -3.0e38f;
  for (int n = t; n < NN; n += 256) m = fmaxf(m, row[n]);
  for (int off = 32; off > 0; off >>= 1) m = fmaxf(m, __shfl_down(m, off));
  __shared__ float ms[4];
  if ((t & 63) == 0) ms[t >> 6] = m;
  __syncthreads();
  if (t == 0) mx[blockIdx.x] = fmaxf(fmaxf(ms[0], ms[1]), fmaxf(ms[2], ms[3]));
}

// ---------------- MFMA attention layer 1 ----------------
// grid (64 i-blocks, 4 heads, 2 j-split), block 256 (4 waves x 16 rows)
__global__ __launch_bounds__(256) void k_att1m(const unsigned short* __restrict__ whbt,
                                               const float* __restrict__ f1, const float* __restrict__ f2,
                                               const float* __restrict__ mx,
                                               const unsigned int* __restrict__ bits32,
                                               float* __restrict__ part) {
  const int h = blockIdx.y, js = blockIdx.z;
  const int t = threadIdx.x;
  const int lane = t & 63, wave = t >> 6;
  const int m = lane & 15, q = lane >> 4;
  const int i0 = blockIdx.x * 64 + wave * 16;
  const int jbase = js * 2048;
  __shared__ float f2s[2048];
  for (int e = t; e < 2048; e += 256) f2s[e] = f2[h * NN + jbase + e];
  __syncthreads();
  const float f1r = f1[h * NN + i0 + m];
  const float fm = f1r + mx[h];
  const float mr = fmaxf(fm, 0.1f * fm);
  const unsigned int* brow = bits32 + (size_t)(i0 + m) * 128 + (jbase >> 5);
  const unsigned short* bb0 = whbt + (size_t)(h * 32 + m) * NN + jbase + q * 8;
  const unsigned short* bb1 = bb0 + 16 * NN;
  const float* fp = f2s + q * 8;
  f32x4 acc0 = {0.f, 0.f, 0.f, 0.f}, acc1 = {0.f, 0.f, 0.f, 0.f};
  for (int step = 0; step < 64; ++step) {
    const int jl = step * 32;
    unsigned bsel = brow[step] >> (q * 8);
    float4 fa = *(const float4*)(fp + jl);
    float4 fb = *(const float4*)(fp + jl + 4);
    float w0 = score(fa.x, f1r, mr, bsel, 0);
    float w1 = score(fa.y, f1r, mr, bsel, 1);
    float w2 = score(fa.z, f1r, mr, bsel, 2);
    float w3 = score(fa.w, f1r, mr, bsel, 3);
    float w4 = score(fb.x, f1r, mr, bsel, 4);
    float w5 = score(fb.y, f1r, mr, bsel, 5);
    float w6 = score(fb.z, f1r, mr, bsel, 6);
    float w7 = score(fb.w, f1r, mr, bsel, 7);
    union { short8_t v; unsigned u[4]; } A;
    A.u[0] = bfpk(w0, w1);
    A.u[1] = bfpk(w2, w3);
    A.u[2] = bfpk(w4, w5);
    A.u[3] = bfpk(w6, w7);
    short8_t b0 = *(const short8_t*)(bb0 + jl);
    short8_t b1 = *(const short8_t*)(bb1 + jl);
    acc0 = __builtin_amdgcn_mfma_f32_16x16x32_bf16(A.v, b0, acc0, 0, 0, 0);
    acc1 = __builtin_amdgcn_mfma_f32_16x16x32_bf16(A.v, b1, acc1, 0, 0, 0);
  }
  float* pp = part + ((size_t)(js * 4 + h) * NN + i0 + q * 4) * 32 + m;
#pragma unroll
  for (int r = 0; r < 4; ++r) {
    pp[r * 32] = acc0[r];
    pp[r * 32 + 16] = acc1[r];
  }
}

// ---------------- combine layer-1 partials -> h1 ----------------
__global__ __launch_bounds__(64) void k_h1(const float* __restrict__ part, const float* __restrict__ b1,
                                           float* __restrict__ h1) {
  int lane = threadIdx.x;
  int p = lane >> 5, o = lane & 31;
  int id = blockIdx.x * 2 + p;  // h*4096+n
  int h = id >> 12, n = id & 4095;
  const float* p0 = part + ((size_t)h * NN + n) * 32 + o;
  const float* p1 = part + ((size_t)(4 + h) * NN + n) * 32 + o;
  float tot = p0[0] + p1[0];
  float l = __shfl(tot, p * 32 + 30);
  if (o < H1PER) h1[(size_t)n * H1DIM + h * H1PER + o] = lrelu(tot / l + b1[h * H1PER + o]);
}

// ---------------- GEMM2: wh2 = h1 @ W2 ----------------
__global__ __launch_bounds__(256) void k_gemm2(const float* __restrict__ h1, const float* __restrict__ W2,
                                               float* __restrict__ wh2) {
  const int n0 = blockIdx.x * 4;
  const int t = threadIdx.x;
  const int o = t & 63, r = t >> 6;
  __shared__ float hs[4][120];
  for (int e = t; e < 4 * H1DIM; e += 256) hs[e / H1DIM][e % H1DIM] = h1[(size_t)n0 * H1DIM + e];
  __syncthreads();
  if (o < H2DIM) {
    float acc = 0.f;
#pragma unroll 4
    for (int k = 0; k < H1DIM; ++k) acc += hs[r][k] * W2[k * H2DIM + o];
    wh2[(size_t)(n0 + r) * H2DIM + o] = acc;
  }
}

// ---------------- layer-2 f1/f2 + bf16 wh2^T ----------------
__global__ __launch_bounds__(256) void k_f2l2(const float* __restrict__ wh2, const float* __restrict__ a2s,
                                              const float* __restrict__ a2d, float* __restrict__ f1,
                                              float* __restrict__ f2, unsigned short* __restrict__ whbt) {
  int n = blockIdx.x * 256 + threadIdx.x;
  if (n >= NN) return;
  const float* r = wh2 + (size_t)n * H2DIM;
  unsigned short* wb = whbt + n;
  float accs = 0.f, accd = 0.f;
#pragma unroll
  for (int j = 0; j < H2DIM; ++j) {
    float v = r[j];
    wb[j * NN] = bfrne(v);
    accs += v * a2s[j];
    accd += v * a2d[j];
  }
  wb[50 * NN] = 0x3f80;
#pragma unroll
  for (int j = 51; j < 64; ++j) wb[j * NN] = 0;
  f1[n] = accs;
  f2[n] = accd;
}

// ---------------- MFMA attention layer 2 ----------------
__global__ __launch_bounds__(256) void k_att2m(const unsigned short* __restrict__ whbt,
                                               const float* __restrict__ f1, const float* __restrict__ f2,
                                               const float* __restrict__ mx,
                                               const unsigned int* __restrict__ bits32,
                                               float* __restrict__ part) {
  const int js = blockIdx.y;
  const int t = threadIdx.x;
  const int lane = t & 63, wave = t >> 6;
  const int m = lane & 15, q = lane >> 4;
  const int i0 = blockIdx.x * 64 + wave * 16;
  const int jbase = js * 1024;
  __shared__ float f2s[1024];
  for (int e = t; e < 1024; e += 256) f2s[e] = f2[jbase + e];
  __syncthreads();
  const float f1r = f1[i0 + m];
  const float fm = f1r + mx[0];
  const float mr = fmaxf(fm, 0.1f * fm);
  const unsigned int* brow = bits32 + (size_t)(i0 + m) * 128 + (jbase >> 5);
  const unsigned short* bb = whbt + (size_t)m * NN + jbase + q * 8;
  const float* fp = f2s + q * 8;
  f32x4 acc[4];
#pragma unroll
  for (int x = 0; x < 4; ++x) acc[x] = (f32x4){0.f, 0.f, 0.f, 0.f};
  for (int step = 0; step < 32; ++step) {
    const int jl = step * 32;
    unsigned bsel = brow[step] >> (q * 8);
    float4 fa = *(const float4*)(fp + jl);
    float4 fb = *(const float4*)(fp + jl + 4);
    float w0 = score(fa.x, f1r, mr, bsel, 0);
    float w1 = score(fa.y, f1r, mr, bsel, 1);
    float w2 = score(fa.z, f1r, mr, bsel, 2);
    float w3 = score(fa.w, f1r, mr, bsel, 3);
    float w4 = score(fb.x, f1r, mr, bsel, 4);
    float w5 = score(fb.y, f1r, mr, bsel, 5);
    float w6 = score(fb.z, f1r, mr, bsel, 6);
    float w7 = score(fb.w, f1r, mr, bsel, 7);
    union { short8_t v; unsigned u[4]; } A;
    A.u[0] = bfpk(w0, w1);
    A.u[1] = bfpk(w2, w3);
    A.u[2] = bfpk(w4, w5);
    A.u[3] = bfpk(w6, w7);
#pragma unroll
    for (int tile = 0; tile < 4; ++tile) {
      short8_t b = *(const short8_t*)(bb + (size_t)tile * 16 * NN + jl);
      acc[tile] = __builtin_amdgcn_mfma_f32_16x16x32_bf16(A.v, b, acc[tile], 0, 0, 0);
    }
  }
  float* pp = part + ((size_t)js * NN + i0 + q * 4) * 64 + m;
#pragma unroll
  for (int tile = 0; tile < 4; ++tile)
#pragma unroll
    for (int r = 0; r < 4; ++r) pp[r * 64 + tile * 16] = acc[tile][r];
}

// ---------------- combine layer-2 partials -> h2 ----------------
__global__ __launch_bounds__(64) void k_h2(const float* __restrict__ part, const float* __restrict__ b2,
                                           float* __restrict__ h2) {
  int n = blockIdx.x;
  int o = threadIdx.x;
  const float* p = part + (size_t)n * 64 + o;
  float tot = p[0] + p[NN * 64] + p[2 * NN * 64] + p[3 * NN * 64];
  float l = __shfl(tot, 50);
  if (o < H2DIM) h2[(size_t)n * H2DIM + o] = lrelu(tot / l + b2[o]);
}

// ---------------- FiLM + logits ----------------
__global__ __launch_bounds__(64) void k_film(const float* __restrict__ l_loc, const float* __restrict__ h2,
                                             const float* __restrict__ Wl1, const float* __restrict__ bl1,
                                             const float* __restrict__ Wl2, const float* __restrict__ bl2,
                                             const float* __restrict__ Wg, const float* __restrict__ bg,
                                             const float* __restrict__ Wb, const float* __restrict__ bb,
                                             const float* __restrict__ Wgate, const float* __restrict__ bgate,
                                             const float* __restrict__ Wc, float* __restrict__ logits) {
  int n = blockIdx.x;
  int lane = threadIdx.x;
  __shared__ float z1s[32], z2s[32], loc_s[16];
  if (lane < 16) loc_s[lane] = l_loc[n * 16 + lane];
  __syncthreads();
  if (lane < 32) {
    float a = bl1[lane];
#pragma unroll
    for (int j = 0; j < 16; ++j) a += Wl1[lane * 16 + j] * loc_s[j];
    z1s[lane] = lrelu(a);
  }
  __syncthreads();
  if (lane < 32) {
    float a = bl2[lane];
#pragma unroll
    for (int j = 0; j < 32; ++j) a += Wl2[lane * 32 + j] * z1s[j];
    z2s[lane] = lrelu(a);
  }
  __syncthreads();
  float gs = bgate[0];
#pragma unroll
  for (int j = 0; j < 32; ++j) gs += Wgate[j] * z2s[j];
  float cov = loc_s[15];
  cov = cov < 0.f ? 0.f : (cov > 1.f ? 1.f : cov);
  float g = (1.f / (1.f + __expf(-gs))) * cov;
  float hf = 0.f;
  int o = lane;
  if (o < H2DIM) {
    float gam = bg[o], bet = bb[o];
#pragma unroll
    for (int j = 0; j < 32; ++j) {
      float z = z2s[j];
      gam += Wg[o * 32 + j] * z;
      bet += Wb[o * 32 + j] * z;
    }
    float hv = h2[(size_t)n * H2DIM + o];
    hf = hv + g * (gam * hv + bet);
  }
  float p0 = (o < H2DIM) ? hf * Wc[o] : 0.f;
  float p1 = (o < H2DIM) ? hf * Wc[H2DIM + o] : 0.f;
  for (int off = 32; off > 0; off >>= 1) {
    p0 += __shfl_down(p0, off);
    p1 += __shfl_down(p1, off);
  }
  if (lane == 0) {
    logits[n * 2 + 0] = lrelu(p0);
    logits[n * 2 + 1] = lrelu(p1);
  }
}

// ---------------- SSDB ----------------
__global__ __launch_bounds__(64) void k_ssdb1(const float* __restrict__ logits, const float* __restrict__ Ws1,
                                              float* __restrict__ hsum) {
  int combo = blockIdx.y;
  int hemi = combo >> 1, c = combo & 1;
  int k = threadIdx.x;
  if (k >= 60) return;
  int nbase = blockIdx.x * 256;
  const float* wrow = Ws1 + (size_t)k * 2048 + nbase;
  const float* lcol = logits + (size_t)(hemi * 2048 + nbase) * 2 + c;
  float part = 0.f;
  for (int q = 0; q < 256; ++q) part += wrow[q] * lcol[2 * q];
  atomicAdd(&hsum[combo * 60 + k], part);
}

__global__ __launch_bounds__(256) void k_ssdb2(const float* __restrict__ hsum, const float* __restrict__ bs1,
                                               const float* __restrict__ Ws2, const float* __restrict__ bs2,
                                               float* __restrict__ B) {
  int t = threadIdx.x;
  int combo = t >> 6, k = t & 63;
  float part = 0.f;
  if (k < 60) part = lrelu(hsum[combo * 60 + k] + bs1[k]) * Ws2[k];
  for (int off = 32; off > 0; off >>= 1) part += __shfl_down(part, off);
  if (k == 0) B[combo] = lrelu(part + bs2[0]);
}

__global__ __launch_bounds__(256) void k_final(const float* __restrict__ logits, const float* __restrict__ B,
                                               float* __restrict__ out) {
  int id = blockIdx.x * 256 + threadIdx.x;
  if (id < 2 * NN) {
    int n = id >> 1, c = id & 1;
    out[id] = logits[id] + B[(n < 2048 ? 0 : 2) + c];
  } else if (id < 2 * NN + 2) {
    int c = id - 2 * NN;
    out[id] = 0.5f * (B[c] + B[2 + c]);
  }
}

// ---------------- workspace layout (float offsets) ----------------
#define OFF_BITS 0          // 524288 (u64 bitmask)
#define OFF_WH1BT 524288    // 262144 (bf16 [4][32][4096])
#define OFF_GP 786432       // 4194304 (gemm1 partials [8][4096][128]; dead after k_f1c)
#define OFF_A1P 786432      // 1048576 (att1 partials; overlays GP)
#define OFF_A2P 524288      // 1048576 (att2 partials; overlays WH1BT+A1P when dead)
#define OFF_F1A 4980736     // 16384
#define OFF_F2A 4997120     // 16384
#define OFF_MX1 5013504     // 64
#define OFF_H1 5013568      // 491520
#define OFF_WH2 5505088     // 204800
#define OFF_WH2BT 5709888   // 131072
#define OFF_F12 5840960     // 4096
#define OFF_F22 5845056     // 4096
#define OFF_MX2 5849152     // 64
#define OFF_H2 5849216      // 204800
#define OFF_LOG 6054016     // 8192
#define OFF_HSUM 6062208    // 256
#define OFF_B 6062464       // 8
#define OFF_W1T 6062592     // 262144 (bf16 [128][4096])

extern "C" void kernel_launch(void* const* d_in, const int* in_sizes, int n_in,
                              void* d_out, int out_size, void* d_ws, size_t ws_size,
                              hipStream_t stream) {
  const float* x_fc  = (const float*)d_in[0];
  const int*   adj   = (const int*)d_in[1];
  const float* l_loc = (const float*)d_in[2];
  const float* W1    = (const float*)d_in[3];
  const float* a1s   = (const float*)d_in[4];
  const float* a1d   = (const float*)d_in[5];
  const float* b1    = (const float*)d_in[6];
  const float* W2    = (const float*)d_in[7];
  const float* a2s   = (const float*)d_in[8];
  const float* a2d   = (const float*)d_in[9];
  const float* b2    = (const float*)d_in[10];
  const float* Wc    = (const float*)d_in[11];
  const float* Wl1   = (const float*)d_in[12];
  const float* bl1   = (const float*)d_in[13];
  const float* Wl2   = (const float*)d_in[14];
  const float* bl2   = (const float*)d_in[15];
  const float* Wg    = (const float*)d_in[16];
  const float* bg    = (const float*)d_in[17];
  const float* Wb    = (const float*)d_in[18];
  const float* bb    = (const float*)d_in[19];
  const float* Wgate = (const float*)d_in[20];
  const float* bgate = (const float*)d_in[21];
  const float* Ws1   = (const float*)d_in[22];
  const float* bs1   = (const float*)d_in[23];
  const float* Ws2   = (const float*)d_in[24];
  const float* bs2   = (const float*)d_in[25];
  float* out = (float*)d_out;
  float* w = (float*)d_ws;
  unsigned long long* bits = (unsigned long long*)(w + OFF_BITS);
  const unsigned int* bits32 = (const unsigned int*)bits;
  unsigned short* wh1bt = (unsigned short*)(w + OFF_WH1BT);
  unsigned short* wh2bt = (unsigned short*)(w + OFF_WH2BT);
  unsigned short* w1t = (unsigned short*)(w + OFF_W1T);

  k_bits<<<NN * NN / 256, 256, 0, stream>>>(adj, bits);
  k_prep<<<16, 256, 0, stream>>>(W1, a1s, a1d, w1t);
  k_gemm1s<<<dim3(64, 8), 256, 0, stream>>>(x_fc, w1t, w + OFF_GP);
  k_f1c<<<256, 256, 0, stream>>>(w + OFF_GP, wh1bt, w + OFF_F1A, w + OFF_F2A);
  k_max<<<HEADS, 256, 0, stream>>>(w + OFF_F2A, w + OFF_MX1);
  k_att1m<<<dim3(64, HEADS, 2), 256, 0, stream>>>(wh1bt, w + OFF_F1A, w + OFF_F2A,
                                                  w + OFF_MX1, bits32, w + OFF_A1P);
  k_h1<<<8192, 64, 0, stream>>>(w + OFF_A1P, b1, w + OFF_H1);
  k_gemm2<<<NN / 4, 256, 0, stream>>>(w + OFF_H1, W2, w + OFF_WH2);
  k_f2l2<<<NN / 256, 256, 0, stream>>>(w + OFF_WH2, a2s, a2d, w + OFF_F12, w + OFF_F22, wh2bt);
  k_max<<<1, 256, 0, stream>>>(w + OFF_F22, w + OFF_MX2);
  k_att2m<<<dim3(64, 4), 256, 0, stream>>>(wh2bt, w + OFF_F12, w + OFF_F22,
                                           w + OFF_MX2, bits32, w + OFF_A2P);
  k_h2<<<NN, 64, 0, stream>>>(w + OFF_A2P, b2, w + OFF_H2);
  k_film<<<NN, 64, 0, stream>>>(l_loc, w + OFF_H2, Wl1, bl1, Wl2, bl2, Wg, bg, Wb, bb,
                                Wgate, bgate, Wc, w + OFF_LOG);
  hipMemsetAsync(w + OFF_HSUM, 0, 240 * sizeof(float), stream);
  k_ssdb1<<<dim3(8, 4), 64, 0, stream>>>(w + OFF_LOG, Ws1, w + OFF_HSUM);
  k_ssdb2<<<1, 256, 0, stream>>>(w + OFF_HSUM, bs1, Ws2, bs2, w + OFF_B);
  k_final<<<(2 * NN + 2 + 255) / 256, 256, 0, stream>>>(w + OFF_LOG, w + OFF_B, out);
}

// Round 5
// 362.148 us; speedup vs baseline: 2.2148x; 1.0644x over previous
//
#include <hip/hip_runtime.h>

#define NN 4096
#define HEADS 4
#define H1PER 30
#define H1DIM 120
#define H2DIM 50

typedef short short8_t __attribute__((ext_vector_type(8)));
typedef float f32x4 __attribute__((ext_vector_type(4)));

__device__ __forceinline__ float lrelu(float x) { return x > 0.f ? x : 0.1f * x; }

// round-to-nearest-even float->bf16
__device__ __forceinline__ unsigned short bfrne(float x) {
  unsigned u = __float_as_uint(x);
  u += 0x7fffu + ((u >> 16) & 1u);
  return (unsigned short)(u >> 16);
}
__device__ __forceinline__ unsigned bfpk_rne(float lo, float hi) {
  return (unsigned)bfrne(lo) | ((unsigned)bfrne(hi) << 16);
}
// pack two floats to bf16x2 (round-half-up; for nonneg alpha weights)
__device__ __forceinline__ unsigned bfpk(float lo, float hi) {
  unsigned a = (__float_as_uint(lo) + 0x8000u) >> 16;
  unsigned b = (__float_as_uint(hi) + 0x8000u) & 0xffff0000u;
  return a | b;
}
// alpha-weight: exp(lrelu(f1+f2) - m) * maskbit
__device__ __forceinline__ float score(float f2v, float f1r, float mr, unsigned bsel, int jj) {
  float f = f1r + f2v;
  float e = fmaxf(f, 0.1f * f);
  float wv = __expf(e - mr);
  return wv * (float)((bsel >> jj) & 1u);
}

// ---------------- bitmask: adj(int32) -> 1 bit (4 elems/thread) ----------------
__global__ __launch_bounds__(256) void k_bits(const int* __restrict__ adj,
                                              unsigned long long* __restrict__ bits) {
  size_t base = (size_t)blockIdx.x * 1024;
  int t = threadIdx.x;
  int v0 = adj[base + t];
  int v1 = adj[base + 256 + t];
  int v2 = adj[base + 512 + t];
  int v3 = adj[base + 768 + t];
  unsigned long long m0 = __ballot(v0 > 0);
  unsigned long long m1 = __ballot(v1 > 0);
  unsigned long long m2 = __ballot(v2 > 0);
  unsigned long long m3 = __ballot(v3 > 0);
  if ((t & 63) == 0) {
    size_t w = (base + t) >> 6;
    bits[w] = m0;
    bits[w + 4] = m1;
    bits[w + 8] = m2;
    bits[w + 12] = m3;
  }
}

// ---------------- prep: W1 -> bf16 w1t[128][4096]; cols 120..127 = f1/f2 features ----------------
__global__ __launch_bounds__(256) void k_prep(const float* __restrict__ W1,
                                              const float* __restrict__ a1s,
                                              const float* __restrict__ a1d,
                                              unsigned short* __restrict__ w1t) {
  int k = blockIdx.x * 256 + threadIdx.x;  // 0..4095
#pragma unroll
  for (int h = 0; h < 4; ++h) {
    const float* wp = W1 + ((size_t)h * 4096 + k) * H1PER;
    float fs = 0.f, fd = 0.f;
#pragma unroll
    for (int oo = 0; oo < H1PER; ++oo) {
      float v = wp[oo];
      w1t[(size_t)(h * 30 + oo) * 4096 + k] = bfrne(v);
      fs += v * a1s[h * H1PER + oo];
      fd += v * a1d[h * H1PER + oo];
    }
    w1t[(size_t)(120 + h) * 4096 + k] = bfrne(fs);
    w1t[(size_t)(124 + h) * 4096 + k] = bfrne(fd);
  }
}

// ---------------- MFMA GEMM1 (LDS-free): part[z] = x[:, z*512:+512] @ w1t^T ----------------
// grid (64 mblocks, 8 ksplit), block 256 (4 waves; wave = 16-row m-tile x 128 cols)
// A-fragment loads straight from global: lane(q,m) reads x[row i0+w*16+m][kc+q*8..+7]
// -> wave covers 16 rows x 128B contiguous = full cache lines, no LDS, no barriers.
__global__ __launch_bounds__(256, 2) void k_gemm1s(const float* __restrict__ x,
                                                   const unsigned short* __restrict__ w1t,
                                                   float* __restrict__ part) {
  const int t = threadIdx.x;
  const int lane = t & 63, wave = t >> 6;
  const int m = lane & 15, q = lane >> 4;
  const int i0 = blockIdx.x * 64;
  const int kz = blockIdx.y * 512;
  const float* xp = x + (size_t)(i0 + wave * 16 + m) * 4096 + kz + q * 8;
  const unsigned short* wb = w1t + (size_t)m * 4096 + kz + q * 8;
  f32x4 acc[8];
#pragma unroll
  for (int nt = 0; nt < 8; ++nt) acc[nt] = (f32x4){0.f, 0.f, 0.f, 0.f};
#pragma unroll 4
  for (int ks = 0; ks < 16; ++ks) {
    float4 a0 = *(const float4*)(xp + ks * 32);
    float4 a1 = *(const float4*)(xp + ks * 32 + 4);
    short8_t Bv[8];
#pragma unroll
    for (int nt = 0; nt < 8; ++nt)
      Bv[nt] = *(const short8_t*)(wb + ks * 32 + (size_t)nt * 16 * 4096);
    union { short8_t v; unsigned u[4]; } A;
    A.u[0] = bfpk_rne(a0.x, a0.y);
    A.u[1] = bfpk_rne(a0.z, a0.w);
    A.u[2] = bfpk_rne(a1.x, a1.y);
    A.u[3] = bfpk_rne(a1.z, a1.w);
#pragma unroll
    for (int nt = 0; nt < 8; ++nt)
      acc[nt] = __builtin_amdgcn_mfma_f32_16x16x32_bf16(A.v, Bv[nt], acc[nt], 0, 0, 0);
  }
  // C/D: row = q*4+reg, col = m (per 16-col n-tile)
  float* pp = part + ((size_t)blockIdx.y * 4096 + i0 + wave * 16 + q * 4) * 128 + m;
#pragma unroll
  for (int nt = 0; nt < 8; ++nt)
#pragma unroll
    for (int r = 0; r < 4; ++r) pp[r * 128 + nt * 16] = acc[nt][r];
}

// ---------------- combine k-split partials -> whbt(bf16,T) + f1/f2 ----------------
// grid 256 blocks, 256 threads: 16 nodes/block, 16 threads/node (8 cols each)
__global__ __launch_bounds__(256) void k_f1c(const float* __restrict__ part,
                                             unsigned short* __restrict__ whbt,
                                             float* __restrict__ f1, float* __restrict__ f2) {
  const int t = threadIdx.x;
  const int n = blockIdx.x * 16 + (t >> 4);
  const int og = (t & 15) * 8;
  float s[8] = {0.f, 0.f, 0.f, 0.f, 0.f, 0.f, 0.f, 0.f};
  for (int z = 0; z < 8; ++z) {
    const float* pp = part + ((size_t)z * NN + n) * 128 + og;
    float4 u0 = *(const float4*)pp;
    float4 u1 = *(const float4*)(pp + 4);
    s[0] += u0.x; s[1] += u0.y; s[2] += u0.z; s[3] += u0.w;
    s[4] += u1.x; s[5] += u1.y; s[6] += u1.z; s[7] += u1.w;
  }
  if (og < 120) {
#pragma unroll
    for (int j = 0; j < 8; ++j) {
      int o = og + j;
      int h = o / 30, oo = o - h * 30;
      whbt[(size_t)(h * 32 + oo) * NN + n] = bfrne(s[j]);
    }
  } else {
#pragma unroll
    for (int j = 0; j < 4; ++j) {
      f1[(size_t)j * NN + n] = s[j];
      f2[(size_t)j * NN + n] = s[4 + j];
    }
  }
  if ((t & 15) < 8) {
    int h = (t & 15) >> 1, odd = (t & 15) & 1;
    whbt[(size_t)(h * 32 + 30 + odd) * NN + n] = odd ? 0 : 0x3f80;
  }
}

// ---------------- per-row max over 4096 values ----------------
__global__ __launch_bounds__(256) void k_max(const float* __restrict__ v, float* __restrict__ mx) {
  int t = threadIdx.x;
  const float* row = v + (size_t)blockIdx.x * NN;
  float m = -3.0e38f;
  for (int n = t; n < NN; n += 256) m = fmaxf(m, row[n]);
  for (int off = 32; off > 0; off >>= 1) m = fmaxf(m, __shfl_down(m, off));
  __shared__ float ms[4];
  if ((t & 63) == 0) ms[t >> 6] = m;
  __syncthreads();
  if (t == 0) mx[blockIdx.x] = fmaxf(fmaxf(ms[0], ms[1]), fmaxf(ms[2], ms[3]));
}

// ---------------- MFMA attention layer 1 ----------------
// grid (64 i-blocks, 4 heads, 2 j-split), block 256 (4 waves x 16 rows)
__global__ __launch_bounds__(256) void k_att1m(const unsigned short* __restrict__ whbt,
                                               const float* __restrict__ f1, const float* __restrict__ f2,
                                               const float* __restrict__ mx,
                                               const unsigned int* __restrict__ bits32,
                                               float* __restrict__ part) {
  const int h = blockIdx.y, js = blockIdx.z;
  const int t = threadIdx.x;
  const int lane = t & 63, wave = t >> 6;
  const int m = lane & 15, q = lane >> 4;
  const int i0 = blockIdx.x * 64 + wave * 16;
  const int jbase = js * 2048;
  __shared__ float f2s[2048];
  for (int e = t; e < 2048; e += 256) f2s[e] = f2[h * NN + jbase + e];
  __syncthreads();
  const float f1r = f1[h * NN + i0 + m];
  const float fm = f1r + mx[h];
  const float mr = fmaxf(fm, 0.1f * fm);
  const unsigned int* brow = bits32 + (size_t)(i0 + m) * 128 + (jbase >> 5);
  const unsigned short* bb0 = whbt + (size_t)(h * 32 + m) * NN + jbase + q * 8;
  const unsigned short* bb1 = bb0 + 16 * NN;
  const float* fp = f2s + q * 8;
  f32x4 acc0 = {0.f, 0.f, 0.f, 0.f}, acc1 = {0.f, 0.f, 0.f, 0.f};
  for (int step = 0; step < 64; ++step) {
    const int jl = step * 32;
    unsigned bsel = brow[step] >> (q * 8);
    float4 fa = *(const float4*)(fp + jl);
    float4 fb = *(const float4*)(fp + jl + 4);
    float w0 = score(fa.x, f1r, mr, bsel, 0);
    float w1 = score(fa.y, f1r, mr, bsel, 1);
    float w2 = score(fa.z, f1r, mr, bsel, 2);
    float w3 = score(fa.w, f1r, mr, bsel, 3);
    float w4 = score(fb.x, f1r, mr, bsel, 4);
    float w5 = score(fb.y, f1r, mr, bsel, 5);
    float w6 = score(fb.z, f1r, mr, bsel, 6);
    float w7 = score(fb.w, f1r, mr, bsel, 7);
    union { short8_t v; unsigned u[4]; } A;
    A.u[0] = bfpk(w0, w1);
    A.u[1] = bfpk(w2, w3);
    A.u[2] = bfpk(w4, w5);
    A.u[3] = bfpk(w6, w7);
    short8_t b0 = *(const short8_t*)(bb0 + jl);
    short8_t b1 = *(const short8_t*)(bb1 + jl);
    acc0 = __builtin_amdgcn_mfma_f32_16x16x32_bf16(A.v, b0, acc0, 0, 0, 0);
    acc1 = __builtin_amdgcn_mfma_f32_16x16x32_bf16(A.v, b1, acc1, 0, 0, 0);
  }
  float* pp = part + ((size_t)(js * 4 + h) * NN + i0 + q * 4) * 32 + m;
#pragma unroll
  for (int r = 0; r < 4; ++r) {
    pp[r * 32] = acc0[r];
    pp[r * 32 + 16] = acc1[r];
  }
}

// ---------------- combine layer-1 partials -> h1 ----------------
// grid 2048, block 256: 8 (h,n) ids per block (16384 total)
__global__ __launch_bounds__(256) void k_h1(const float* __restrict__ part, const float* __restrict__ b1,
                                            float* __restrict__ h1) {
  int t = threadIdx.x;
  int lane = t & 63;
  int p = lane >> 5, o = lane & 31;
  int id = blockIdx.x * 8 + (t >> 6) * 2 + p;  // h*4096+n
  int h = id >> 12, n = id & 4095;
  const float* p0 = part + ((size_t)h * NN + n) * 32 + o;
  const float* p1 = part + ((size_t)(4 + h) * NN + n) * 32 + o;
  float tot = p0[0] + p1[0];
  float l = __shfl(tot, p * 32 + 30);
  if (o < H1PER) h1[(size_t)n * H1DIM + h * H1PER + o] = lrelu(tot / l + b1[h * H1PER + o]);
}

// ---------------- GEMM2: wh2 = h1 @ W2 ----------------
__global__ __launch_bounds__(256) void k_gemm2(const float* __restrict__ h1, const float* __restrict__ W2,
                                               float* __restrict__ wh2) {
  const int n0 = blockIdx.x * 4;
  const int t = threadIdx.x;
  const int o = t & 63, r = t >> 6;
  __shared__ float hs[4][120];
  for (int e = t; e < 4 * H1DIM; e += 256) hs[e / H1DIM][e % H1DIM] = h1[(size_t)n0 * H1DIM + e];
  __syncthreads();
  if (o < H2DIM) {
    float acc = 0.f;
#pragma unroll 4
    for (int k = 0; k < H1DIM; ++k) acc += hs[r][k] * W2[k * H2DIM + o];
    wh2[(size_t)(n0 + r) * H2DIM + o] = acc;
  }
}

// ---------------- layer-2 f1/f2 + bf16 wh2^T ----------------
__global__ __launch_bounds__(256) void k_f2l2(const float* __restrict__ wh2, const float* __restrict__ a2s,
                                              const float* __restrict__ a2d, float* __restrict__ f1,
                                              float* __restrict__ f2, unsigned short* __restrict__ whbt) {
  int n = blockIdx.x * 256 + threadIdx.x;
  if (n >= NN) return;
  const float* r = wh2 + (size_t)n * H2DIM;
  unsigned short* wb = whbt + n;
  float accs = 0.f, accd = 0.f;
#pragma unroll
  for (int j = 0; j < H2DIM; ++j) {
    float v = r[j];
    wb[j * NN] = bfrne(v);
    accs += v * a2s[j];
    accd += v * a2d[j];
  }
  wb[50 * NN] = 0x3f80;
#pragma unroll
  for (int j = 51; j < 64; ++j) wb[j * NN] = 0;
  f1[n] = accs;
  f2[n] = accd;
}

// ---------------- MFMA attention layer 2 ----------------
__global__ __launch_bounds__(256) void k_att2m(const unsigned short* __restrict__ whbt,
                                               const float* __restrict__ f1, const float* __restrict__ f2,
                                               const float* __restrict__ mx,
                                               const unsigned int* __restrict__ bits32,
                                               float* __restrict__ part) {
  const int js = blockIdx.y;
  const int t = threadIdx.x;
  const int lane = t & 63, wave = t >> 6;
  const int m = lane & 15, q = lane >> 4;
  const int i0 = blockIdx.x * 64 + wave * 16;
  const int jbase = js * 1024;
  __shared__ float f2s[1024];
  for (int e = t; e < 1024; e += 256) f2s[e] = f2[jbase + e];
  __syncthreads();
  const float f1r = f1[i0 + m];
  const float fm = f1r + mx[0];
  const float mr = fmaxf(fm, 0.1f * fm);
  const unsigned int* brow = bits32 + (size_t)(i0 + m) * 128 + (jbase >> 5);
  const unsigned short* bb = whbt + (size_t)m * NN + jbase + q * 8;
  const float* fp = f2s + q * 8;
  f32x4 acc[4];
#pragma unroll
  for (int x = 0; x < 4; ++x) acc[x] = (f32x4){0.f, 0.f, 0.f, 0.f};
  for (int step = 0; step < 32; ++step) {
    const int jl = step * 32;
    unsigned bsel = brow[step] >> (q * 8);
    float4 fa = *(const float4*)(fp + jl);
    float4 fb = *(const float4*)(fp + jl + 4);
    float w0 = score(fa.x, f1r, mr, bsel, 0);
    float w1 = score(fa.y, f1r, mr, bsel, 1);
    float w2 = score(fa.z, f1r, mr, bsel, 2);
    float w3 = score(fa.w, f1r, mr, bsel, 3);
    float w4 = score(fb.x, f1r, mr, bsel, 4);
    float w5 = score(fb.y, f1r, mr, bsel, 5);
    float w6 = score(fb.z, f1r, mr, bsel, 6);
    float w7 = score(fb.w, f1r, mr, bsel, 7);
    union { short8_t v; unsigned u[4]; } A;
    A.u[0] = bfpk(w0, w1);
    A.u[1] = bfpk(w2, w3);
    A.u[2] = bfpk(w4, w5);
    A.u[3] = bfpk(w6, w7);
#pragma unroll
    for (int tile = 0; tile < 4; ++tile) {
      short8_t b = *(const short8_t*)(bb + (size_t)tile * 16 * NN + jl);
      acc[tile] = __builtin_amdgcn_mfma_f32_16x16x32_bf16(A.v, b, acc[tile], 0, 0, 0);
    }
  }
  float* pp = part + ((size_t)js * NN + i0 + q * 4) * 64 + m;
#pragma unroll
  for (int tile = 0; tile < 4; ++tile)
#pragma unroll
    for (int r = 0; r < 4; ++r) pp[r * 64 + tile * 16] = acc[tile][r];
}

// ---------------- combine layer-2 partials -> h2 ----------------
__global__ __launch_bounds__(64) void k_h2(const float* __restrict__ part, const float* __restrict__ b2,
                                           float* __restrict__ h2) {
  int n = blockIdx.x;
  int o = threadIdx.x;
  const float* p = part + (size_t)n * 64 + o;
  float tot = p[0] + p[NN * 64] + p[2 * NN * 64] + p[3 * NN * 64];
  float l = __shfl(tot, 50);
  if (o < H2DIM) h2[(size_t)n * H2DIM + o] = lrelu(tot / l + b2[o]);
}

// ---------------- FiLM + logits (wave-local, shuffle-based; 4 nodes/block) ----------------
__global__ __launch_bounds__(256) void k_film(const float* __restrict__ l_loc, const float* __restrict__ h2,
                                              const float* __restrict__ Wl1, const float* __restrict__ bl1,
                                              const float* __restrict__ Wl2, const float* __restrict__ bl2,
                                              const float* __restrict__ Wg, const float* __restrict__ bg,
                                              const float* __restrict__ Wb, const float* __restrict__ bb,
                                              const float* __restrict__ Wgate, const float* __restrict__ bgate,
                                              const float* __restrict__ Wc, float* __restrict__ logits) {
  int n = blockIdx.x * 4 + (threadIdx.x >> 6);
  int lane = threadIdx.x & 63;
  int r32 = lane & 31;
  float locv = l_loc[n * 16 + (lane & 15)];
  float cov = __shfl(locv, 15);
  cov = fminf(fmaxf(cov, 0.f), 1.f);
  float a1v = bl1[r32];
#pragma unroll
  for (int j = 0; j < 16; ++j) a1v += Wl1[r32 * 16 + j] * __shfl(locv, j);
  float z1 = lrelu(a1v);
  float a2v = bl2[r32];
#pragma unroll
  for (int j = 0; j < 32; ++j) a2v += Wl2[r32 * 32 + j] * __shfl(z1, j);
  float z2 = lrelu(a2v);
  float gs = bgate[0];
  float gam, bet;
  {
    int o = lane < H2DIM ? lane : 0;
    gam = bg[o];
    bet = bb[o];
#pragma unroll
    for (int j = 0; j < 32; ++j) {
      float zj = __shfl(z2, j);
      gs += Wgate[j] * zj;
      gam += Wg[o * 32 + j] * zj;
      bet += Wb[o * 32 + j] * zj;
    }
  }
  float g = cov / (1.f + __expf(-gs));
  int o = lane < H2DIM ? lane : 0;
  float hv = h2[(size_t)n * H2DIM + o];
  float hf = hv + g * (gam * hv + bet);
  float p0 = lane < H2DIM ? hf * Wc[o] : 0.f;
  float p1 = lane < H2DIM ? hf * Wc[H2DIM + o] : 0.f;
  for (int off = 32; off > 0; off >>= 1) {
    p0 += __shfl_down(p0, off);
    p1 += __shfl_down(p1, off);
  }
  if (lane == 0) {
    logits[n * 2 + 0] = lrelu(p0);
    logits[n * 2 + 1] = lrelu(p1);
  }
}

// ---------------- SSDB ----------------
__global__ __launch_bounds__(64) void k_ssdb1(const float* __restrict__ logits, const float* __restrict__ Ws1,
                                              float* __restrict__ hsum) {
  int combo = blockIdx.y;
  int hemi = combo >> 1, c = combo & 1;
  int k = threadIdx.x;
  if (k >= 60) return;
  int nbase = blockIdx.x * 256;
  const float* wrow = Ws1 + (size_t)k * 2048 + nbase;
  const float* lcol = logits + (size_t)(hemi * 2048 + nbase) * 2 + c;
  float part = 0.f;
  for (int q = 0; q < 256; ++q) part += wrow[q] * lcol[2 * q];
  atomicAdd(&hsum[combo * 60 + k], part);
}

__global__ __launch_bounds__(256) void k_ssdb2(const float* __restrict__ hsum, const float* __restrict__ bs1,
                                               const float* __restrict__ Ws2, const float* __restrict__ bs2,
                                               float* __restrict__ B) {
  int t = threadIdx.x;
  int combo = t >> 6, k = t & 63;
  float part = 0.f;
  if (k < 60) part = lrelu(hsum[combo * 60 + k] + bs1[k]) * Ws2[k];
  for (int off = 32; off > 0; off >>= 1) part += __shfl_down(part, off);
  if (k == 0) B[combo] = lrelu(part + bs2[0]);
}

__global__ __launch_bounds__(256) void k_final(const float* __restrict__ logits, const float* __restrict__ B,
                                               float* __restrict__ out) {
  int id = blockIdx.x * 256 + threadIdx.x;
  if (id < 2 * NN) {
    int n = id >> 1, c = id & 1;
    out[id] = logits[id] + B[(n < 2048 ? 0 : 2) + c];
  } else if (id < 2 * NN + 2) {
    int c = id - 2 * NN;
    out[id] = 0.5f * (B[c] + B[2 + c]);
  }
}

// ---------------- workspace layout (float offsets) ----------------
#define OFF_BITS 0          // 524288 (u64 bitmask)
#define OFF_WH1BT 524288    // 262144 (bf16 [4][32][4096])
#define OFF_GP 786432       // 4194304 (gemm1 partials [8][4096][128]; dead after k_f1c)
#define OFF_A1P 786432      // 1048576 (att1 partials; overlays GP)
#define OFF_A2P 524288      // 1048576 (att2 partials; overlays WH1BT+A1P when dead)
#define OFF_F1A 4980736     // 16384
#define OFF_F2A 4997120     // 16384
#define OFF_MX1 5013504     // 64
#define OFF_H1 5013568      // 491520
#define OFF_WH2 5505088     // 204800
#define OFF_WH2BT 5709888   // 131072
#define OFF_F12 5840960     // 4096
#define OFF_F22 5845056     // 4096
#define OFF_MX2 5849152     // 64
#define OFF_H2 5849216      // 204800
#define OFF_LOG 6054016     // 8192
#define OFF_HSUM 6062208    // 256
#define OFF_B 6062464       // 8
#define OFF_W1T 6062592     // 262144 (bf16 [128][4096])

extern "C" void kernel_launch(void* const* d_in, const int* in_sizes, int n_in,
                              void* d_out, int out_size, void* d_ws, size_t ws_size,
                              hipStream_t stream) {
  const float* x_fc  = (const float*)d_in[0];
  const int*   adj   = (const int*)d_in[1];
  const float* l_loc = (const float*)d_in[2];
  const float* W1    = (const float*)d_in[3];
  const float* a1s   = (const float*)d_in[4];
  const float* a1d   = (const float*)d_in[5];
  const float* b1    = (const float*)d_in[6];
  const float* W2    = (const float*)d_in[7];
  const float* a2s   = (const float*)d_in[8];
  const float* a2d   = (const float*)d_in[9];
  const float* b2    = (const float*)d_in[10];
  const float* Wc    = (const float*)d_in[11];
  const float* Wl1   = (const float*)d_in[12];
  const float* bl1   = (const float*)d_in[13];
  const float* Wl2   = (const float*)d_in[14];
  const float* bl2   = (const float*)d_in[15];
  const float* Wg    = (const float*)d_in[16];
  const float* bg    = (const float*)d_in[17];
  const float* Wb    = (const float*)d_in[18];
  const float* bb    = (const float*)d_in[19];
  const float* Wgate = (const float*)d_in[20];
  const float* bgate = (const float*)d_in[21];
  const float* Ws1   = (const float*)d_in[22];
  const float* bs1   = (const float*)d_in[23];
  const float* Ws2   = (const float*)d_in[24];
  const float* bs2   = (const float*)d_in[25];
  float* out = (float*)d_out;
  float* w = (float*)d_ws;
  unsigned long long* bits = (unsigned long long*)(w + OFF_BITS);
  const unsigned int* bits32 = (const unsigned int*)bits;
  unsigned short* wh1bt = (unsigned short*)(w + OFF_WH1BT);
  unsigned short* wh2bt = (unsigned short*)(w + OFF_WH2BT);
  unsigned short* w1t = (unsigned short*)(w + OFF_W1T);

  k_bits<<<NN * NN / 1024, 256, 0, stream>>>(adj, bits);
  k_prep<<<16, 256, 0, stream>>>(W1, a1s, a1d, w1t);
  k_gemm1s<<<dim3(64, 8), 256, 0, stream>>>(x_fc, w1t, w + OFF_GP);
  k_f1c<<<256, 256, 0, stream>>>(w + OFF_GP, wh1bt, w + OFF_F1A, w + OFF_F2A);
  k_max<<<HEADS, 256, 0, stream>>>(w + OFF_F2A, w + OFF_MX1);
  k_att1m<<<dim3(64, HEADS, 2), 256, 0, stream>>>(wh1bt, w + OFF_F1A, w + OFF_F2A,
                                                  w + OFF_MX1, bits32, w + OFF_A1P);
  k_h1<<<2048, 256, 0, stream>>>(w + OFF_A1P, b1, w + OFF_H1);
  k_gemm2<<<NN / 4, 256, 0, stream>>>(w + OFF_H1, W2, w + OFF_WH2);
  k_f2l2<<<NN / 256, 256, 0, stream>>>(w + OFF_WH2, a2s, a2d, w + OFF_F12, w + OFF_F22, wh2bt);
  k_max<<<1, 256, 0, stream>>>(w + OFF_F22, w + OFF_MX2);
  k_att2m<<<dim3(64, 4), 256, 0, stream>>>(wh2bt, w + OFF_F12, w + OFF_F22,
                                           w + OFF_MX2, bits32, w + OFF_A2P);
  k_h2<<<NN, 64, 0, stream>>>(w + OFF_A2P, b2, w + OFF_H2);
  k_film<<<NN / 4, 256, 0, stream>>>(l_loc, w + OFF_H2, Wl1, bl1, Wl2, bl2, Wg, bg, Wb, bb,
                                     Wgate, bgate, Wc, w + OFF_LOG);
  hipMemsetAsync(w + OFF_HSUM, 0, 240 * sizeof(float), stream);
  k_ssdb1<<<dim3(8, 4), 64, 0, stream>>>(w + OFF_LOG, Ws1, w + OFF_HSUM);
  k_ssdb2<<<1, 256, 0, stream>>>(w + OFF_HSUM, bs1, Ws2, bs2, w + OFF_B);
  k_final<<<(2 * NN + 2 + 255) / 256, 256, 0, stream>>>(w + OFF_LOG, w + OFF_B, out);
}